// Round 13
// baseline (465.532 us; speedup 1.0000x reference)
//
#include <hip/hip_runtime.h>
#include <cstdint>

typedef __bf16 bf16;
typedef __bf16 bf16x2 __attribute__((ext_vector_type(2)));
typedef __bf16 bf16x4 __attribute__((ext_vector_type(4)));
typedef __bf16 bf16x8 __attribute__((ext_vector_type(8)));
typedef float f32x4 __attribute__((ext_vector_type(4)));

#define MROWS 16384
#define DIMH 1024
#define PDIM 512
#define LSEQ 4096
#define CL 16
#define NC (LSEQ / CL)  // 256

typedef const __attribute__((address_space(1))) unsigned int* gas_t;
typedef __attribute__((address_space(3))) unsigned int* las_t;

__device__ __forceinline__ float gelu_f(float x) {
  return 0.5f * x * (1.0f + erff(x * 0.70710678118654752f));
}

// ---------------------------------------------------------------- mega prep
__global__ __launch_bounds__(256) void k_mega(
    const float* __restrict__ x, const float* __restrict__ W_in,
    const float* __restrict__ W_out, const float* __restrict__ ffe,
    const float* __restrict__ ffd, const float* __restrict__ Lre,
    const float* __restrict__ Lim, const float* __restrict__ lstep,
    const float* __restrict__ Bre, const float* __restrict__ Bim,
    const float* __restrict__ Cre, const float* __restrict__ Cim,
    bf16* __restrict__ xb, bf16* __restrict__ winb, bf16* __restrict__ woutb,
    bf16* __restrict__ ffeb, bf16* __restrict__ ffdb, bf16* __restrict__ bcat,
    bf16* __restrict__ cc, float2* __restrict__ lamb) {
  const int bid = blockIdx.x;
  const int tid = threadIdx.x;
  auto cvt4 = [&](const float* src, bf16* dst, int i4) {
    const float4 v = *(const float4*)(src + i4);
    bf16x4 o = { (bf16)v.x, (bf16)v.y, (bf16)v.z, (bf16)v.w };
    *(bf16x4*)(dst + i4) = o;
  };
  if (bid < 8192) {
    cvt4(x, xb, bid * 1024 + tid * 4);
  } else if (bid < 8704) {
    cvt4(W_in, winb, (bid - 8192) * 1024 + tid * 4);
  } else if (bid < 9216) {
    cvt4(W_out, woutb, (bid - 8704) * 1024 + tid * 4);
  } else if (bid < 11264) {
    cvt4(ffe, ffeb, (bid - 9216) * 1024 + tid * 4);
  } else if (bid < 12288) {
    cvt4(ffd, ffdb, (bid - 11264) * 1024 + tid * 4);
  } else if (bid < 12800) {
    const int i4 = (bid - 12288) * 1024 + tid * 4;
    const int p = i4 >> 10;
    const float lre = Lre[p], lim = Lim[p];
    const float st = expf(lstep[p]);
    const float er = expf(lre * st);
    const float lbr = er * cosf(lim * st);
    const float lbi = er * sinf(lim * st);
    const float ar = lbr - 1.0f, ai = lbi;
    const float d = lre * lre + lim * lim;
    const float cx = (ar * lre + ai * lim) / d;
    const float cy = (ai * lre - ar * lim) / d;
    const float4 br = *(const float4*)(Bre + i4);
    const float4 bi = *(const float4*)(Bim + i4);
    bf16x4 o1 = { (bf16)(cx * br.x - cy * bi.x), (bf16)(cx * br.y - cy * bi.y),
                  (bf16)(cx * br.z - cy * bi.z), (bf16)(cx * br.w - cy * bi.w) };
    bf16x4 o2 = { (bf16)(cx * bi.x + cy * br.x), (bf16)(cx * bi.y + cy * br.y),
                  (bf16)(cx * bi.z + cy * br.z), (bf16)(cx * bi.w + cy * br.w) };
    *(bf16x4*)(bcat + i4) = o1;
    *(bf16x4*)(bcat + i4 + PDIM * DIMH) = o2;
  } else if (bid < 14848) {
    const int i4 = (bid - 12800) * 1024 + tid * 4;
    const int n = i4 >> 11, k0 = i4 & 2047;
    const float* src;
    float sgn;
    int kk;
    if (k0 < 512)       { src = Cre + n * 1024;       sgn =  2.0f; kk = k0; }
    else if (k0 < 1024) { src = Cim + n * 1024;       sgn = -2.0f; kk = k0 - 512; }
    else if (k0 < 1536) { src = Cre + n * 1024 + 512; sgn =  2.0f; kk = k0 - 1024; }
    else                { src = Cim + n * 1024 + 512; sgn = -2.0f; kk = k0 - 1536; }
    const float4 v = *(const float4*)(src + kk);
    bf16x4 o = { (bf16)(sgn * v.x), (bf16)(sgn * v.y), (bf16)(sgn * v.z), (bf16)(sgn * v.w) };
    *(bf16x4*)(cc + i4) = o;
  } else {
    const int p = (bid - 14848) * 256 + tid;
    if (p < PDIM) {
      const float lre = Lre[p], lim = Lim[p];
      const float st = expf(lstep[p]);
      const float er = expf(lre * st);
      lamb[p] = make_float2(er * cosf(lim * st), er * sinf(lim * st));
    }
  }
}

#define VMCNT4 asm volatile("s_waitcnt vmcnt(4)" ::: "memory")
#define VMCNT0 asm volatile("s_waitcnt vmcnt(0)" ::: "memory")
#define LGKM0  asm volatile("s_waitcnt lgkmcnt(0)" ::: "memory")
#define SCHED0 __builtin_amdgcn_sched_barrier(0)
#define BAR    __builtin_amdgcn_s_barrier()

// ---------------------------------------------------------------- GEMM A (128x128, 3-buffer, 1 barrier/unit, 3 blocks/CU)
// EPI: 0 = f32 store; 3 = bf16 store.
template <int EPI>
__global__ __launch_bounds__(256, 3) void k_gemm(const bf16* __restrict__ A,
                                                 const bf16* __restrict__ W,
                                                 float* __restrict__ Cf,
                                                 bf16* __restrict__ Cb,
                                                 int K, int N, int nbnl) {
  extern __shared__ char lds[];  // 49152 bytes: 3 x (A 8KB + B 8KB)
  const int q = (int)gridDim.x >> 3;
  const int s = ((int)blockIdx.x & 7) * q + ((int)blockIdx.x >> 3);
  const int bm = s >> nbnl;
  const int bn = s & ((1 << nbnl) - 1);
  const int tid = threadIdx.x;
  const int lane = tid & 63;
  const int wave = tid >> 6;   // 0..3
  const int wr = wave >> 1;    // 0..1
  const int wc = wave & 1;     // 0..1

  const size_t arow0 = (size_t)bm * 128;
  const size_t wrow0 = (size_t)bn * 128;
  const int srow = tid >> 2;                         // 0..63 per issue
  const int schunk = (tid & 3) ^ ((tid >> 3) & 3);   // inverse-swizzled src chunk
  const int wbase = wave << 10;

  f32x4 acc[4][4];
#pragma unroll
  for (int i = 0; i < 4; ++i)
#pragma unroll
    for (int j = 0; j < 4; ++j) acc[i][j] = (f32x4){0.f, 0.f, 0.f, 0.f};

  auto stage = [&](int buf, int ui) {
    const int kcol = ui * 32 + schunk * 8;
    char* ba = lds + buf * 16384;
    __builtin_amdgcn_global_load_lds(
        (gas_t)(A + (arow0 + srow) * (size_t)K + kcol), (las_t)(ba + wbase), 16, 0, 0);
    __builtin_amdgcn_global_load_lds(
        (gas_t)(A + (arow0 + 64 + srow) * (size_t)K + kcol), (las_t)(ba + 4096 + wbase), 16, 0, 0);
    char* bb = ba + 8192;
    __builtin_amdgcn_global_load_lds(
        (gas_t)(W + (wrow0 + srow) * (size_t)K + kcol), (las_t)(bb + wbase), 16, 0, 0);
    __builtin_amdgcn_global_load_lds(
        (gas_t)(W + (wrow0 + 64 + srow) * (size_t)K + kcol), (las_t)(bb + 4096 + wbase), 16, 0, 0);
  };

  auto ldA = [&](int buf, bf16x8* af) {
#pragma unroll
    for (int m = 0; m < 4; ++m) {
      const int row = wr * 64 + m * 16 + (lane & 15);
      const int pc = (lane >> 4) ^ ((row >> 1) & 3);
      af[m] = *(const bf16x8*)(lds + buf * 16384 + row * 64 + pc * 16);
    }
  };
  auto ldB = [&](int buf, bf16x8* bf) {
#pragma unroll
    for (int n = 0; n < 4; ++n) {
      const int row = wc * 64 + n * 16 + (lane & 15);
      const int pc = (lane >> 4) ^ ((row >> 1) & 3);
      bf[n] = *(const bf16x8*)(lds + buf * 16384 + 8192 + row * 64 + pc * 16);
    }
  };

  bf16x8 afr[4], bfr[4];

  stage(0, 0);
  stage(1, 1);
  VMCNT4;
  BAR;

  const int NU = K >> 5;  // units of 32 K-cols
  int buf = 0, sbuf = 2;
  for (int u = 0; u < NU; ++u) {
    ldB(buf, bfr);
    ldA(buf, afr);
    if (u + 2 < NU) stage(sbuf, u + 2);
    LGKM0; SCHED0;
    __builtin_amdgcn_s_setprio(1);
#pragma unroll
    for (int m = 0; m < 4; ++m)
#pragma unroll
      for (int n = 0; n < 4; ++n)
        acc[m][n] = __builtin_amdgcn_mfma_f32_16x16x32_bf16(afr[m], bfr[n], acc[m][n], 0, 0, 0);
    __builtin_amdgcn_s_setprio(0);
    SCHED0;
    if (u + 2 < NU) { VMCNT4; }
    else if (u + 1 < NU) { VMCNT0; }
    BAR;
    buf = (buf == 2) ? 0 : buf + 1;
    sbuf = (sbuf == 2) ? 0 : sbuf + 1;
  }

  const int n0 = (int)wrow0 + wc * 64 + (lane & 15);
  const size_t m0 = arow0 + wr * 64 + ((lane >> 4) << 2);
#pragma unroll
  for (int mi = 0; mi < 4; ++mi)
#pragma unroll
    for (int n = 0; n < 4; ++n) {
      const size_t mb = m0 + mi * 16;
      const int nn = n0 + n * 16;
#pragma unroll
      for (int r = 0; r < 4; ++r) {
        const size_t idx = (mb + r) * (size_t)N + nn;
        const float v = acc[mi][n][r];
        if constexpr (EPI == 0) {
          Cf[idx] = v;
        } else {
          Cb[idx] = (bf16)v;
        }
      }
    }
}

// ---------------------------------------------------------------- GEMM B (256x256 8-phase convoy — for K=2048)
#define PHASE2(slot, kh, mh, LOADB, STAGE_STMT, WAIT_STMT)                     \
  {                                                                            \
    if (LOADB) ldB(slot, kh, bfr);                                             \
    ldA(slot, kh, mh, afr);                                                    \
    STAGE_STMT;                                                                \
    SCHED0;                                                                    \
    BAR;                                                                       \
    LGKM0;                                                                     \
    SCHED0;                                                                    \
    __builtin_amdgcn_s_setprio(1);                                             \
    _Pragma("unroll")                                                          \
    for (int m = 0; m < 4; ++m)                                                \
      _Pragma("unroll")                                                        \
      for (int n = 0; n < 4; ++n)                                              \
        acc[(mh) * 4 + m][n] = __builtin_amdgcn_mfma_f32_16x16x32_bf16(        \
            afr[m], bfr[n], acc[(mh) * 4 + m][n], 0, 0, 0);                    \
    __builtin_amdgcn_s_setprio(0);                                             \
    SCHED0;                                                                    \
    WAIT_STMT;                                                                 \
    BAR;                                                                       \
  }

template <int EPI>
__global__ __launch_bounds__(512, 2) void k_gemm2(const bf16* __restrict__ A,
                                                  const bf16* __restrict__ W,
                                                  float* __restrict__ Cf,
                                                  bf16* __restrict__ Cb,
                                                  int K, int N, int nbnl) {
  extern __shared__ char lds[];  // 131072 bytes
  const int q = (int)gridDim.x >> 3;
  const int s = ((int)blockIdx.x & 7) * q + ((int)blockIdx.x >> 3);
  const int bm = s >> nbnl;
  const int bn = s & ((1 << nbnl) - 1);
  const int tid = threadIdx.x;
  const int lane = tid & 63;
  const int wave = tid >> 6;
  const int wr = wave >> 2;  // 0..1
  const int wc = wave & 3;   // 0..3

  const size_t arow0 = (size_t)bm * 256;
  const size_t wrow0 = (size_t)bn * 256;
  const int srow = tid >> 2;                         // 0..127 per issue
  const int schunk = (tid & 3) ^ ((tid >> 3) & 3);
  const int wbase = wave << 10;

  f32x4 acc[8][4];
#pragma unroll
  for (int i = 0; i < 8; ++i)
#pragma unroll
    for (int j = 0; j < 4; ++j) acc[i][j] = (f32x4){0.f, 0.f, 0.f, 0.f};

  auto stage = [&](int slot, int kh, int kt) {
    const int kcol = kt * 64 + kh * 32 + schunk * 8;
    {
      char* base = lds + slot * 32768 + kh * 16384;
      __builtin_amdgcn_global_load_lds(
          (gas_t)(A + (arow0 + srow) * (size_t)K + kcol), (las_t)(base + wbase), 16, 0, 0);
      __builtin_amdgcn_global_load_lds(
          (gas_t)(A + (arow0 + 128 + srow) * (size_t)K + kcol), (las_t)(base + 8192 + wbase), 16, 0, 0);
    }
    {
      char* base = lds + 65536 + slot * 32768 + kh * 16384;
      __builtin_amdgcn_global_load_lds(
          (gas_t)(W + (wrow0 + srow) * (size_t)K + kcol), (las_t)(base + wbase), 16, 0, 0);
      __builtin_amdgcn_global_load_lds(
          (gas_t)(W + (wrow0 + 128 + srow) * (size_t)K + kcol), (las_t)(base + 8192 + wbase), 16, 0, 0);
    }
  };

  auto ldA = [&](int slot, int kh, int mh, bf16x8* af) {
#pragma unroll
    for (int m = 0; m < 4; ++m) {
      const int row = wr * 128 + mh * 64 + m * 16 + (lane & 15);
      const int pc = (lane >> 4) ^ ((row >> 1) & 3);
      af[m] = *(const bf16x8*)(lds + slot * 32768 + kh * 16384 + row * 64 + pc * 16);
    }
  };
  auto ldB = [&](int slot, int kh, bf16x8* bf) {
#pragma unroll
    for (int n = 0; n < 4; ++n) {
      const int row = wc * 64 + n * 16 + (lane & 15);
      const int pc = (lane >> 4) ^ ((row >> 1) & 3);
      bf[n] = *(const bf16x8*)(lds + 65536 + slot * 32768 + kh * 16384 + row * 64 + pc * 16);
    }
  };

  bf16x8 afr[4], bfr[4];

  stage(0, 0, 0);
  stage(0, 1, 0);
  stage(1, 0, 1);
  VMCNT4;
  BAR;

  const int NT = K >> 7;
  for (int t = 0; t < NT; ++t) {
    const int nl = (t + 1 < NT);
    PHASE2(0, 0, 0, 1, stage(1, 1, 2 * t + 1), (void)0);
    PHASE2(0, 0, 1, 0, (void)0, (void)0);
    PHASE2(0, 1, 0, 1, if (nl) stage(0, 0, 2 * t + 2), (void)0);
    if (nl) { PHASE2(0, 1, 1, 0, (void)0, VMCNT4); }
    else    { PHASE2(0, 1, 1, 0, (void)0, VMCNT0); }
    PHASE2(1, 0, 0, 1, if (nl) stage(0, 1, 2 * t + 2), (void)0);
    PHASE2(1, 0, 1, 0, (void)0, (void)0);
    PHASE2(1, 1, 0, 1, if (nl) stage(1, 0, 2 * t + 3), (void)0);
    if (nl) { PHASE2(1, 1, 1, 0, (void)0, VMCNT4); }
    else    { PHASE2(1, 1, 1, 0, (void)0, (void)0); }
  }

  const int n0 = (int)wrow0 + wc * 64 + (lane & 15);
  const size_t m0 = arow0 + wr * 128 + ((lane >> 4) << 2);
#pragma unroll
  for (int mi = 0; mi < 8; ++mi)
#pragma unroll
    for (int n = 0; n < 4; ++n) {
      const size_t mb = m0 + mi * 16;
      const int nn = n0 + n * 16;
#pragma unroll
      for (int r = 0; r < 4; ++r) {
        const size_t idx = (mb + r) * (size_t)N + nn;
        const float v = acc[mi][n][r];
        if constexpr (EPI == 0) {
          Cf[idx] = v;
        } else {
          Cb[idx] = (bf16)v;
        }
      }
    }
}

// ---------------------------------------------------------------- elementwise epilogues (coalesced)
// G[i] = A[i] * gelu(Gh[i])
__global__ __launch_bounds__(256) void k_geglu(const bf16* __restrict__ Ah,
                                               const bf16* __restrict__ Gh,
                                               bf16* __restrict__ G) {
  const size_t i = ((size_t)blockIdx.x * 256 + threadIdx.x) * 4;
  const bf16x4 a4 = *(const bf16x4*)(Ah + i);
  const bf16x4 g4 = *(const bf16x4*)(Gh + i);
  bf16x4 o = { (bf16)((float)a4[0] * gelu_f((float)g4[0])),
               (bf16)((float)a4[1] * gelu_f((float)g4[1])),
               (bf16)((float)a4[2] * gelu_f((float)g4[2])),
               (bf16)((float)a4[3] * gelu_f((float)g4[3])) };
  *(bf16x4*)(G + i) = o;
}

// x3[i] = FFO[i] + FX2[i]
__global__ __launch_bounds__(256) void k_addb(const bf16* __restrict__ FFO,
                                              const bf16* __restrict__ FX2,
                                              bf16* __restrict__ X3) {
  const size_t i = ((size_t)blockIdx.x * 256 + threadIdx.x) * 4;
  const bf16x4 a = *(const bf16x4*)(FFO + i);
  const bf16x4 b = *(const bf16x4*)(FX2 + i);
  bf16x4 o = { (bf16)((float)a[0] + (float)b[0]), (bf16)((float)a[1] + (float)b[1]),
               (bf16)((float)a[2] + (float)b[2]), (bf16)((float)a[3] + (float)b[3]) };
  *(bf16x4*)(X3 + i) = o;
}

// ---------------------------------------------------------------- LayerNorm (bf16 in/out)
__global__ __launch_bounds__(256) void k_ln(const bf16* __restrict__ X,
                                            const float* __restrict__ w,
                                            const float* __restrict__ bb,
                                            bf16* __restrict__ Yb) {
  const int m = blockIdx.x;
  const int tid = threadIdx.x;
  const bf16x4 v4 = *(const bf16x4*)(X + (size_t)m * DIMH + tid * 4);
  const float v0 = (float)v4[0], v1 = (float)v4[1], v2 = (float)v4[2], v3 = (float)v4[3];
  float s = v0 + v1 + v2 + v3;
  float s2 = v0 * v0 + v1 * v1 + v2 * v2 + v3 * v3;
#pragma unroll
  for (int off = 32; off > 0; off >>= 1) { s += __shfl_down(s, off); s2 += __shfl_down(s2, off); }
  __shared__ float rs[4], rq[4];
  if ((tid & 63) == 0) { rs[tid >> 6] = s; rq[tid >> 6] = s2; }
  __syncthreads();
  s = rs[0] + rs[1] + rs[2] + rs[3];
  s2 = rq[0] + rq[1] + rq[2] + rq[3];
  const float mu = s * (1.0f / DIMH);
  const float inv = rsqrtf(s2 * (1.0f / DIMH) - mu * mu + 1e-5f);
  const float4 wv = ((const float4*)w)[tid];
  const float4 bv = ((const float4*)bb)[tid];
  bf16x4 ob = { (bf16)((v0 - mu) * inv * wv.x + bv.x), (bf16)((v1 - mu) * inv * wv.y + bv.y),
                (bf16)((v2 - mu) * inv * wv.z + bv.z), (bf16)((v3 - mu) * inv * wv.w + bv.w) };
  *(bf16x4*)(Yb + (size_t)m * DIMH + tid * 4) = ob;
}

// fused: t = gelu(ys + D*fx) + fx ; LN(t) -> fx2, in-place into FXE
__global__ __launch_bounds__(256) void k_ln2e(const bf16* __restrict__ YS,
                                              bf16* FXE,
                                              const float* __restrict__ Dv,
                                              const float* __restrict__ w,
                                              const float* __restrict__ bb) {
  const int m = blockIdx.x;
  const int tid = threadIdx.x;
  const bf16x4 ys4 = *(const bf16x4*)(YS + (size_t)m * DIMH + tid * 4);
  const bf16x4 fx4 = *(const bf16x4*)(FXE + (size_t)m * DIMH + tid * 4);
  const float4 dv = ((const float4*)Dv)[tid];
  const float f0 = (float)fx4[0], f1 = (float)fx4[1], f2 = (float)fx4[2], f3 = (float)fx4[3];
  const float t0 = gelu_f((float)ys4[0] + dv.x * f0) + f0;
  const float t1 = gelu_f((float)ys4[1] + dv.y * f1) + f1;
  const float t2 = gelu_f((float)ys4[2] + dv.z * f2) + f2;
  const float t3 = gelu_f((float)ys4[3] + dv.w * f3) + f3;
  float s = t0 + t1 + t2 + t3;
  float s2 = t0 * t0 + t1 * t1 + t2 * t2 + t3 * t3;
#pragma unroll
  for (int off = 32; off > 0; off >>= 1) { s += __shfl_down(s, off); s2 += __shfl_down(s2, off); }
  __shared__ float rs[4], rq[4];
  if ((tid & 63) == 0) { rs[tid >> 6] = s; rq[tid >> 6] = s2; }
  __syncthreads();
  s = rs[0] + rs[1] + rs[2] + rs[3];
  s2 = rq[0] + rq[1] + rq[2] + rq[3];
  const float mu = s * (1.0f / DIMH);
  const float inv = rsqrtf(s2 * (1.0f / DIMH) - mu * mu + 1e-5f);
  const float4 wv = ((const float4*)w)[tid];
  const float4 bv = ((const float4*)bb)[tid];
  bf16x4 ob = { (bf16)((t0 - mu) * inv * wv.x + bv.x), (bf16)((t1 - mu) * inv * wv.y + bv.y),
                (bf16)((t2 - mu) * inv * wv.z + bv.z), (bf16)((t3 - mu) * inv * wv.w + bv.w) };
  *(bf16x4*)(FXE + (size_t)m * DIMH + tid * 4) = ob;
}

// ---------------------------------------------------------------- scan (3-pass, bf16 Bu)
__global__ __launch_bounds__(256) void k_scanA(const bf16* __restrict__ Bu,
                                               const float2* __restrict__ lamb,
                                               float2* __restrict__ carry) {
  const int bc = blockIdx.x;
  const int b = bc >> 8, c = bc & (NC - 1);
  const int t = threadIdx.x;
  const size_t rbase = ((size_t)b * LSEQ + (size_t)c * CL) * DIMH;
  float2 re[CL], im[CL];
#pragma unroll
  for (int i = 0; i < CL; ++i) {
    const bf16x2 r2 = *(const bf16x2*)(Bu + rbase + (size_t)i * DIMH + 2 * t);
    const bf16x2 i2 = *(const bf16x2*)(Bu + rbase + (size_t)i * DIMH + PDIM + 2 * t);
    re[i] = make_float2((float)r2[0], (float)r2[1]);
    im[i] = make_float2((float)i2[0], (float)i2[1]);
  }
  const float2 l0 = lamb[2 * t];
  const float2 l1 = lamb[2 * t + 1];
  const size_t cb = ((size_t)bc * 2) * PDIM;
  {
    float s0r = 0.f, s0i = 0.f, s1r = 0.f, s1i = 0.f;
#pragma unroll
    for (int i = 0; i < CL; ++i) {
      float nr = l0.x * s0r - l0.y * s0i + re[i].x;
      float ni = l0.x * s0i + l0.y * s0r + im[i].x;
      s0r = nr; s0i = ni;
      nr = l1.x * s1r - l1.y * s1i + re[i].y;
      ni = l1.x * s1i + l1.y * s1r + im[i].y;
      s1r = nr; s1i = ni;
    }
    carry[cb + 2 * t]     = make_float2(s0r, s0i);
    carry[cb + 2 * t + 1] = make_float2(s1r, s1i);
  }
  {
    float s0r = 0.f, s0i = 0.f, s1r = 0.f, s1i = 0.f;
#pragma unroll
    for (int i = CL - 1; i >= 0; --i) {
      float nr = l0.x * s0r - l0.y * s0i + re[i].x;
      float ni = l0.x * s0i + l0.y * s0r + im[i].x;
      s0r = nr; s0i = ni;
      nr = l1.x * s1r - l1.y * s1i + re[i].y;
      ni = l1.x * s1i + l1.y * s1r + im[i].y;
      s1r = nr; s1i = ni;
    }
    carry[cb + PDIM + 2 * t]     = make_float2(s0r, s0i);
    carry[cb + PDIM + 2 * t + 1] = make_float2(s1r, s1i);
  }
}

__global__ __launch_bounds__(256) void k_scanB(const float2* __restrict__ carry,
                                               const float2* __restrict__ lamb,
                                               float2* __restrict__ seed) {
  const int b = blockIdx.x;  // 4 blocks
  const int t = threadIdx.x;
  const float2 l0 = lamb[2 * t], l1 = lamb[2 * t + 1];
  float L0r = l0.x, L0i = l0.y, L1r = l1.x, L1i = l1.y;
#pragma unroll
  for (int q = 0; q < 4; ++q) {
    float tr = L0r * L0r - L0i * L0i; L0i = 2.f * L0r * L0i; L0r = tr;
    tr = L1r * L1r - L1i * L1i; L1i = 2.f * L1r * L1i; L1r = tr;
  }
  float S0r = 0.f, S0i = 0.f, S1r = 0.f, S1i = 0.f;
  for (int c = 0; c < NC; ++c) {
    const size_t base = (((size_t)b * NC + c) * 2) * PDIM;
    const float2 c0 = carry[base + 2 * t];
    const float2 c1 = carry[base + 2 * t + 1];
    seed[base + 2 * t]     = make_float2(S0r, S0i);
    seed[base + 2 * t + 1] = make_float2(S1r, S1i);
    float nr = L0r * S0r - L0i * S0i + c0.x;
    float ni = L0r * S0i + L0i * S0r + c0.y;
    S0r = nr; S0i = ni;
    nr = L1r * S1r - L1i * S1i + c1.x;
    ni = L1r * S1i + L1i * S1r + c1.y;
    S1r = nr; S1i = ni;
  }
  S0r = 0.f; S0i = 0.f; S1r = 0.f; S1i = 0.f;
  for (int c = NC - 1; c >= 0; --c) {
    const size_t base = (((size_t)b * NC + c) * 2) * PDIM + PDIM;
    const float2 c0 = carry[base + 2 * t];
    const float2 c1 = carry[base + 2 * t + 1];
    seed[base + 2 * t]     = make_float2(S0r, S0i);
    seed[base + 2 * t + 1] = make_float2(S1r, S1i);
    float nr = L0r * S0r - L0i * S0i + c0.x;
    float ni = L0r * S0i + L0i * S0r + c0.y;
    S0r = nr; S0i = ni;
    nr = L1r * S1r - L1i * S1i + c1.x;
    ni = L1r * S1i + L1i * S1r + c1.y;
    S1r = nr; S1i = ni;
  }
}

__global__ __launch_bounds__(256) void k_scanC(const bf16* __restrict__ Bu,
                                               const float2* __restrict__ lamb,
                                               const float2* __restrict__ seed,
                                               bf16* __restrict__ xs) {
  const int bc = blockIdx.x;
  const int b = bc >> 8, c = bc & (NC - 1);
  const int t = threadIdx.x;
  const size_t rbase = ((size_t)b * LSEQ + (size_t)c * CL) * DIMH;
  float2 re[CL], im[CL];
#pragma unroll
  for (int i = 0; i < CL; ++i) {
    const bf16x2 r2 = *(const bf16x2*)(Bu + rbase + (size_t)i * DIMH + 2 * t);
    const bf16x2 i2 = *(const bf16x2*)(Bu + rbase + (size_t)i * DIMH + PDIM + 2 * t);
    re[i] = make_float2((float)r2[0], (float)r2[1]);
    im[i] = make_float2((float)i2[0], (float)i2[1]);
  }
  const float2 l0 = lamb[2 * t];
  const float2 l1 = lamb[2 * t + 1];
  const size_t sb = ((size_t)bc * 2) * PDIM;
  const size_t obase = ((size_t)b * LSEQ + (size_t)c * CL) * 2048;
  {
    const float2 s0 = seed[sb + 2 * t];
    const float2 s1 = seed[sb + 2 * t + 1];
    float s0r = s0.x, s0i = s0.y, s1r = s1.x, s1i = s1.y;
#pragma unroll
    for (int i = 0; i < CL; ++i) {
      float nr = l0.x * s0r - l0.y * s0i + re[i].x;
      float ni = l0.x * s0i + l0.y * s0r + im[i].x;
      s0r = nr; s0i = ni;
      nr = l1.x * s1r - l1.y * s1i + re[i].y;
      ni = l1.x * s1i + l1.y * s1r + im[i].y;
      s1r = nr; s1i = ni;
      bf16x2 wr2 = { (bf16)s0r, (bf16)s1r };
      bf16x2 wi2 = { (bf16)s0i, (bf16)s1i };
      *(bf16x2*)(xs + obase + (size_t)i * 2048 + 2 * t) = wr2;
      *(bf16x2*)(xs + obase + (size_t)i * 2048 + PDIM + 2 * t) = wi2;
    }
  }
  {
    const float2 s0 = seed[sb + PDIM + 2 * t];
    const float2 s1 = seed[sb + PDIM + 2 * t + 1];
    float s0r = s0.x, s0i = s0.y, s1r = s1.x, s1i = s1.y;
#pragma unroll
    for (int i = CL - 1; i >= 0; --i) {
      float nr = l0.x * s0r - l0.y * s0i + re[i].x;
      float ni = l0.x * s0i + l0.y * s0r + im[i].x;
      s0r = nr; s0i = ni;
      nr = l1.x * s1r - l1.y * s1i + re[i].y;
      ni = l1.x * s1i + l1.y * s1r + im[i].y;
      s1r = nr; s1i = ni;
      bf16x2 wr2 = { (bf16)s0r, (bf16)s1r };
      bf16x2 wi2 = { (bf16)s0i, (bf16)s1i };
      *(bf16x2*)(xs + obase + (size_t)i * 2048 + 1024 + 2 * t) = wr2;
      *(bf16x2*)(xs + obase + (size_t)i * 2048 + 1536 + 2 * t) = wi2;
    }
  }
}

// ---------------------------------------------------------------- launch
extern "C" void kernel_launch(void* const* d_in, const int* in_sizes, int n_in,
                              void* d_out, int out_size, void* d_ws, size_t ws_size,
                              hipStream_t stream) {
  const float* x    = (const float*)d_in[0];
  const float* W_in = (const float*)d_in[1];
  const float* W_out= (const float*)d_in[2];
  const float* ln1w = (const float*)d_in[3];
  const float* ln1b = (const float*)d_in[4];
  const float* ln2w = (const float*)d_in[5];
  const float* ln2b = (const float*)d_in[6];
  const float* Lre  = (const float*)d_in[7];
  const float* Lim  = (const float*)d_in[8];
  const float* lstep= (const float*)d_in[9];
  const float* Bre  = (const float*)d_in[10];
  const float* Bim  = (const float*)d_in[11];
  const float* Cre  = (const float*)d_in[12];
  const float* Cim  = (const float*)d_in[13];
  const float* Dv   = (const float*)d_in[14];
  const float* ffe  = (const float*)d_in[15];
  const float* ffd  = (const float*)d_in[16];
  float* out = (float*)d_out;
  char* ws = (char*)d_ws;

  bf16* winb   = (bf16*)(ws);
  bf16* woutb  = (bf16*)(ws + (1u << 20));
  bf16* bcat   = (bf16*)(ws + (2u << 20));
  bf16* ccomb  = (bf16*)(ws + (4u << 20));
  bf16* ffeb   = (bf16*)(ws + (8u << 20));   // 2048x1024: rows 0-1023 = a, 1024-2047 = g
  bf16* ffdb   = (bf16*)(ws + (12u << 20));
  float2* lamb = (float2*)(ws + (14u << 20));
  bf16* E      = (bf16*)(ws + (16u << 20));        // 32MB: x_b -> fx -> fx2
  bf16* hb     = (bf16*)(ws + (48u << 20));        // 32MB: h
  bf16* Bub    = (bf16*)(ws + (48u << 20));        // reuse (h dead after k_ln)
  bf16* ysb    = (bf16*)(ws + (48u << 20));        // reuse (Bu dead after scanC)
  bf16* x3b    = (bf16*)(ws + (48u << 20));        // reuse (ys dead after ln2e)
  bf16* xsb    = (bf16*)(ws + (80u << 20));        // 64MB: xs (80..144)
  bf16* AGa    = (bf16*)(ws + (80u << 20));        // reuse: 32MB (xs dead after C-proj)
  bf16* AGg    = (bf16*)(ws + (112u << 20));       // reuse: 32MB
  bf16* FFO    = (bf16*)(ws + (80u << 20));        // reuse: 32MB (AGa dead after geglu)
  bf16* G      = (bf16*)(ws + (144u << 20));       // 32MB
  float2* carry = (float2*)(ws + (176u << 20));    // 8MB
  float2* seed  = (float2*)(ws + (184u << 20));    // 8MB

  static bool attr_done = false;
  if (!attr_done) {
    hipFuncSetAttribute((const void*)&k_gemm<0>, hipFuncAttributeMaxDynamicSharedMemorySize, 49152);
    hipFuncSetAttribute((const void*)&k_gemm<3>, hipFuncAttributeMaxDynamicSharedMemorySize, 49152);
    hipFuncSetAttribute((const void*)&k_gemm2<3>, hipFuncAttributeMaxDynamicSharedMemorySize, 131072);
    attr_done = true;
  }

  // prep: one mega launch
  k_mega<<<14850, 256, 0, stream>>>(x, W_in, W_out, ffe, ffd, Lre, Lim, lstep,
                                    Bre, Bim, Cre, Cim,
                                    E, winb, woutb, ffeb, ffdb, bcat, ccomb, lamb);

  // h = x @ W_in^T -> hb (bf16)
  k_gemm<3><<<1024, 256, 49152, stream>>>(E, winb, nullptr, hb, 512, 1024, 3);
  // fx = LN1(h) -> E (bf16)
  k_ln<<<16384, 256, 0, stream>>>(hb, ln1w, ln1b, E);
  // Bu = fx @ Bcat^T -> Bub (bf16)
  k_gemm<3><<<1024, 256, 49152, stream>>>(E, bcat, nullptr, Bub, 1024, 1024, 3);
  // xs -> xsb (bf16) via 3-pass chunked scan
  k_scanA<<<4 * NC, 256, 0, stream>>>(Bub, lamb, carry);
  k_scanB<<<4, 256, 0, stream>>>(carry, lamb, seed);
  k_scanC<<<4 * NC, 256, 0, stream>>>(Bub, lamb, seed, xsb);
  // ys = xs @ Ccomb^T -> ysb (bf16): 256x256 kernel (K=2048)
  k_gemm2<3><<<256, 512, 131072, stream>>>(xsb, ccomb, nullptr, ysb, 2048, 1024, 2);
  // x2 = gelu(ys + D*fx) + fx; fx2 = LN2(x2) -> E in place (bf16)
  k_ln2e<<<16384, 256, 0, stream>>>(ysb, E, Dv, ln2w, ln2b);
  // a-half: AGa = fx2 @ ffe_a^T (N=1024, L2-resident W)
  k_gemm<3><<<1024, 256, 49152, stream>>>(E, ffeb, nullptr, AGa, 1024, 1024, 3);
  // g-half: AGg = fx2 @ ffe_g^T
  k_gemm<3><<<1024, 256, 49152, stream>>>(E, ffeb + (size_t)1024 * 1024, nullptr, AGg, 1024, 1024, 3);
  // geglu elementwise: G = a * gelu(g)
  k_geglu<<<16384, 256, 0, stream>>>(AGa, AGg, G);
  // ffo = G @ ffd^T -> FFO (bf16)
  k_gemm<3><<<1024, 256, 49152, stream>>>(G, ffdb, nullptr, FFO, 1024, 1024, 3);
  // x3 = ffo + fx2 -> x3b
  k_addb<<<16384, 256, 0, stream>>>(FFO, E, x3b);
  // out = x3 @ W_out^T (f32)
  k_gemm<0><<<512, 256, 49152, stream>>>(x3b, woutb, out, nullptr, 1024, 512, 2);
}

// Round 15
// 448.063 us; speedup vs baseline: 1.0390x; 1.0390x over previous
//
#include <hip/hip_runtime.h>
#include <cstdint>

typedef __bf16 bf16;
typedef __bf16 bf16x2 __attribute__((ext_vector_type(2)));
typedef __bf16 bf16x4 __attribute__((ext_vector_type(4)));
typedef __bf16 bf16x8 __attribute__((ext_vector_type(8)));
typedef float f32x4 __attribute__((ext_vector_type(4)));

#define MROWS 16384
#define DIMH 1024
#define PDIM 512
#define LSEQ 4096
#define CL 16
#define NC (LSEQ / CL)  // 256

typedef const __attribute__((address_space(1))) unsigned int* gas_t;
typedef __attribute__((address_space(3))) unsigned int* las_t;

__device__ __forceinline__ float gelu_f(float x) {
  return 0.5f * x * (1.0f + erff(x * 0.70710678118654752f));
}

// ---------------------------------------------------------------- mega prep
__global__ __launch_bounds__(256) void k_mega(
    const float* __restrict__ x, const float* __restrict__ W_in,
    const float* __restrict__ W_out, const float* __restrict__ ffe,
    const float* __restrict__ ffd, const float* __restrict__ Lre,
    const float* __restrict__ Lim, const float* __restrict__ lstep,
    const float* __restrict__ Bre, const float* __restrict__ Bim,
    const float* __restrict__ Cre, const float* __restrict__ Cim,
    bf16* __restrict__ xb, bf16* __restrict__ winb, bf16* __restrict__ woutb,
    bf16* __restrict__ ffeb, bf16* __restrict__ ffdb, bf16* __restrict__ bcat,
    bf16* __restrict__ cc, float2* __restrict__ lamb) {
  const int bid = blockIdx.x;
  const int tid = threadIdx.x;
  auto cvt4 = [&](const float* src, bf16* dst, int i4) {
    const float4 v = *(const float4*)(src + i4);
    bf16x4 o = { (bf16)v.x, (bf16)v.y, (bf16)v.z, (bf16)v.w };
    *(bf16x4*)(dst + i4) = o;
  };
  if (bid < 8192) {
    cvt4(x, xb, bid * 1024 + tid * 4);
  } else if (bid < 8704) {
    cvt4(W_in, winb, (bid - 8192) * 1024 + tid * 4);
  } else if (bid < 9216) {
    cvt4(W_out, woutb, (bid - 8704) * 1024 + tid * 4);
  } else if (bid < 11264) {
    cvt4(ffe, ffeb, (bid - 9216) * 1024 + tid * 4);
  } else if (bid < 12288) {
    cvt4(ffd, ffdb, (bid - 11264) * 1024 + tid * 4);
  } else if (bid < 12800) {
    const int i4 = (bid - 12288) * 1024 + tid * 4;
    const int p = i4 >> 10;
    const float lre = Lre[p], lim = Lim[p];
    const float st = expf(lstep[p]);
    const float er = expf(lre * st);
    const float lbr = er * cosf(lim * st);
    const float lbi = er * sinf(lim * st);
    const float ar = lbr - 1.0f, ai = lbi;
    const float d = lre * lre + lim * lim;
    const float cx = (ar * lre + ai * lim) / d;
    const float cy = (ai * lre - ar * lim) / d;
    const float4 br = *(const float4*)(Bre + i4);
    const float4 bi = *(const float4*)(Bim + i4);
    bf16x4 o1 = { (bf16)(cx * br.x - cy * bi.x), (bf16)(cx * br.y - cy * bi.y),
                  (bf16)(cx * br.z - cy * bi.z), (bf16)(cx * br.w - cy * bi.w) };
    bf16x4 o2 = { (bf16)(cx * bi.x + cy * br.x), (bf16)(cx * bi.y + cy * br.y),
                  (bf16)(cx * bi.z + cy * br.z), (bf16)(cx * bi.w + cy * br.w) };
    *(bf16x4*)(bcat + i4) = o1;
    *(bf16x4*)(bcat + i4 + PDIM * DIMH) = o2;
  } else if (bid < 14848) {
    const int i4 = (bid - 12800) * 1024 + tid * 4;
    const int n = i4 >> 11, k0 = i4 & 2047;
    const float* src;
    float sgn;
    int kk;
    if (k0 < 512)       { src = Cre + n * 1024;       sgn =  2.0f; kk = k0; }
    else if (k0 < 1024) { src = Cim + n * 1024;       sgn = -2.0f; kk = k0 - 512; }
    else if (k0 < 1536) { src = Cre + n * 1024 + 512; sgn =  2.0f; kk = k0 - 1024; }
    else                { src = Cim + n * 1024 + 512; sgn = -2.0f; kk = k0 - 1536; }
    const float4 v = *(const float4*)(src + kk);
    bf16x4 o = { (bf16)(sgn * v.x), (bf16)(sgn * v.y), (bf16)(sgn * v.z), (bf16)(sgn * v.w) };
    *(bf16x4*)(cc + i4) = o;
  } else {
    const int p = (bid - 14848) * 256 + tid;
    if (p < PDIM) {
      const float lre = Lre[p], lim = Lim[p];
      const float st = expf(lstep[p]);
      const float er = expf(lre * st);
      lamb[p] = make_float2(er * cosf(lim * st), er * sinf(lim * st));
    }
  }
}

#define VMCNT4 asm volatile("s_waitcnt vmcnt(4)" ::: "memory")
#define VMCNT0 asm volatile("s_waitcnt vmcnt(0)" ::: "memory")
#define LGKM0  asm volatile("s_waitcnt lgkmcnt(0)" ::: "memory")
#define SCHED0 __builtin_amdgcn_sched_barrier(0)
#define BAR    __builtin_amdgcn_s_barrier()

// ---------------------------------------------------------------- GEMM A (128x128, 3-buffer, 1 barrier/unit, 3 blocks/CU)
// EPI: 0 = f32 store; 1 = bf16(auxb * gelu(acc)); 2 = bf16(acc + auxb); 3 = bf16.
template <int EPI>
__global__ __launch_bounds__(256, 3) void k_gemm(const bf16* __restrict__ A,
                                                 const bf16* __restrict__ W,
                                                 float* __restrict__ Cf,
                                                 bf16* __restrict__ Cb,
                                                 const bf16* __restrict__ auxb,
                                                 int K, int N, int nbnl) {
  extern __shared__ char lds[];  // 49152 bytes: 3 x (A 8KB + B 8KB)
  const int q = (int)gridDim.x >> 3;
  const int s = ((int)blockIdx.x & 7) * q + ((int)blockIdx.x >> 3);
  const int bm = s >> nbnl;
  const int bn = s & ((1 << nbnl) - 1);
  const int tid = threadIdx.x;
  const int lane = tid & 63;
  const int wave = tid >> 6;   // 0..3
  const int wr = wave >> 1;    // 0..1
  const int wc = wave & 1;     // 0..1

  const size_t arow0 = (size_t)bm * 128;
  const size_t wrow0 = (size_t)bn * 128;
  const int srow = tid >> 2;                         // 0..63 per issue
  const int schunk = (tid & 3) ^ ((tid >> 3) & 3);   // inverse-swizzled src chunk
  const int wbase = wave << 10;

  f32x4 acc[4][4];
#pragma unroll
  for (int i = 0; i < 4; ++i)
#pragma unroll
    for (int j = 0; j < 4; ++j) acc[i][j] = (f32x4){0.f, 0.f, 0.f, 0.f};

  auto stage = [&](int buf, int ui) {
    const int kcol = ui * 32 + schunk * 8;
    char* ba = lds + buf * 16384;
    __builtin_amdgcn_global_load_lds(
        (gas_t)(A + (arow0 + srow) * (size_t)K + kcol), (las_t)(ba + wbase), 16, 0, 0);
    __builtin_amdgcn_global_load_lds(
        (gas_t)(A + (arow0 + 64 + srow) * (size_t)K + kcol), (las_t)(ba + 4096 + wbase), 16, 0, 0);
    char* bb = ba + 8192;
    __builtin_amdgcn_global_load_lds(
        (gas_t)(W + (wrow0 + srow) * (size_t)K + kcol), (las_t)(bb + wbase), 16, 0, 0);
    __builtin_amdgcn_global_load_lds(
        (gas_t)(W + (wrow0 + 64 + srow) * (size_t)K + kcol), (las_t)(bb + 4096 + wbase), 16, 0, 0);
  };

  auto ldA = [&](int buf, bf16x8* af) {
#pragma unroll
    for (int m = 0; m < 4; ++m) {
      const int row = wr * 64 + m * 16 + (lane & 15);
      const int pc = (lane >> 4) ^ ((row >> 1) & 3);
      af[m] = *(const bf16x8*)(lds + buf * 16384 + row * 64 + pc * 16);
    }
  };
  auto ldB = [&](int buf, bf16x8* bf) {
#pragma unroll
    for (int n = 0; n < 4; ++n) {
      const int row = wc * 64 + n * 16 + (lane & 15);
      const int pc = (lane >> 4) ^ ((row >> 1) & 3);
      bf[n] = *(const bf16x8*)(lds + buf * 16384 + 8192 + row * 64 + pc * 16);
    }
  };

  bf16x8 afr[4], bfr[4];

  stage(0, 0);
  stage(1, 1);
  VMCNT4;
  BAR;

  const int NU = K >> 5;  // units of 32 K-cols
  int buf = 0, sbuf = 2;
  for (int u = 0; u < NU; ++u) {
    ldB(buf, bfr);
    ldA(buf, afr);
    if (u + 2 < NU) stage(sbuf, u + 2);
    LGKM0; SCHED0;
    __builtin_amdgcn_s_setprio(1);
#pragma unroll
    for (int m = 0; m < 4; ++m)
#pragma unroll
      for (int n = 0; n < 4; ++n)
        acc[m][n] = __builtin_amdgcn_mfma_f32_16x16x32_bf16(afr[m], bfr[n], acc[m][n], 0, 0, 0);
    __builtin_amdgcn_s_setprio(0);
    SCHED0;
    if (u + 2 < NU) { VMCNT4; }
    else if (u + 1 < NU) { VMCNT0; }
    BAR;
    buf = (buf == 2) ? 0 : buf + 1;
    sbuf = (sbuf == 2) ? 0 : sbuf + 1;
  }

  const int n0 = (int)wrow0 + wc * 64 + (lane & 15);
  const size_t m0 = arow0 + wr * 64 + ((lane >> 4) << 2);
#pragma unroll
  for (int mi = 0; mi < 4; ++mi)
#pragma unroll
    for (int n = 0; n < 4; ++n) {
      const size_t mb = m0 + mi * 16;
      const int nn = n0 + n * 16;
#pragma unroll
      for (int r = 0; r < 4; ++r) {
        const size_t idx = (mb + r) * (size_t)N + nn;
        const float v = acc[mi][n][r];
        if constexpr (EPI == 0) {
          Cf[idx] = v;
        } else if constexpr (EPI == 1) {
          Cb[idx] = (bf16)((float)auxb[idx] * gelu_f(v));
        } else if constexpr (EPI == 2) {
          Cb[idx] = (bf16)(v + (float)auxb[idx]);
        } else {
          Cb[idx] = (bf16)v;
        }
      }
    }
}

// ---------------------------------------------------------------- GEMM B (256x256, 3-buffer rotation, 1 barrier/unit)
// For K=2048 (C-proj). unit = 32 K-cols, LDS 3 x (A 16KB + B 16KB) = 96 KB.
template <int EPI>
__global__ __launch_bounds__(512, 1) void k_gemm2(const bf16* __restrict__ A,
                                                  const bf16* __restrict__ W,
                                                  float* __restrict__ Cf,
                                                  bf16* __restrict__ Cb,
                                                  int K, int N, int nbnl) {
  extern __shared__ char lds[];  // 98304 bytes
  const int q = (int)gridDim.x >> 3;
  const int s = ((int)blockIdx.x & 7) * q + ((int)blockIdx.x >> 3);
  const int bm = s >> nbnl;
  const int bn = s & ((1 << nbnl) - 1);
  const int tid = threadIdx.x;
  const int lane = tid & 63;
  const int wave = tid >> 6;
  const int wr = wave >> 2;  // 0..1
  const int wc = wave & 3;   // 0..3

  const size_t arow0 = (size_t)bm * 256;
  const size_t wrow0 = (size_t)bn * 256;
  const int srow = tid >> 2;                         // 0..127 per issue
  const int schunk = (tid & 3) ^ ((tid >> 3) & 3);
  const int wbase = wave << 10;

  f32x4 acc[8][4];
#pragma unroll
  for (int i = 0; i < 8; ++i)
#pragma unroll
    for (int j = 0; j < 4; ++j) acc[i][j] = (f32x4){0.f, 0.f, 0.f, 0.f};

  auto stage = [&](int buf, int ui) {
    const int kcol = ui * 32 + schunk * 8;
    char* ba = lds + buf * 32768;
    __builtin_amdgcn_global_load_lds(
        (gas_t)(A + (arow0 + srow) * (size_t)K + kcol), (las_t)(ba + wbase), 16, 0, 0);
    __builtin_amdgcn_global_load_lds(
        (gas_t)(A + (arow0 + 128 + srow) * (size_t)K + kcol), (las_t)(ba + 8192 + wbase), 16, 0, 0);
    char* bb = ba + 16384;
    __builtin_amdgcn_global_load_lds(
        (gas_t)(W + (wrow0 + srow) * (size_t)K + kcol), (las_t)(bb + wbase), 16, 0, 0);
    __builtin_amdgcn_global_load_lds(
        (gas_t)(W + (wrow0 + 128 + srow) * (size_t)K + kcol), (las_t)(bb + 8192 + wbase), 16, 0, 0);
  };

  auto ldA = [&](int buf, bf16x8* af) {
#pragma unroll
    for (int m = 0; m < 8; ++m) {
      const int row = wr * 128 + m * 16 + (lane & 15);
      const int pc = (lane >> 4) ^ ((row >> 1) & 3);
      af[m] = *(const bf16x8*)(lds + buf * 32768 + row * 64 + pc * 16);
    }
  };
  auto ldB = [&](int buf, bf16x8* bf) {
#pragma unroll
    for (int n = 0; n < 4; ++n) {
      const int row = wc * 64 + n * 16 + (lane & 15);
      const int pc = (lane >> 4) ^ ((row >> 1) & 3);
      bf[n] = *(const bf16x8*)(lds + buf * 32768 + 16384 + row * 64 + pc * 16);
    }
  };

  bf16x8 afr[8], bfr[4];

  stage(0, 0);
  stage(1, 1);
  VMCNT4;
  BAR;

  const int NU = K >> 5;  // 64 units for K=2048
  int buf = 0, sbuf = 2;
  for (int u = 0; u < NU; ++u) {
    ldB(buf, bfr);
    ldA(buf, afr);
    if (u + 2 < NU) stage(sbuf, u + 2);
    LGKM0; SCHED0;
    __builtin_amdgcn_s_setprio(1);
#pragma unroll
    for (int m = 0; m < 8; ++m)
#pragma unroll
      for (int n = 0; n < 4; ++n)
        acc[m][n] = __builtin_amdgcn_mfma_f32_16x16x32_bf16(afr[m], bfr[n], acc[m][n], 0, 0, 0);
    __builtin_amdgcn_s_setprio(0);
    SCHED0;
    if (u + 2 < NU) { VMCNT4; }
    else if (u + 1 < NU) { VMCNT0; }
    BAR;
    buf = (buf == 2) ? 0 : buf + 1;
    sbuf = (sbuf == 2) ? 0 : sbuf + 1;
  }

  const int n0 = (int)wrow0 + wc * 64 + (lane & 15);
  const size_t m0 = arow0 + wr * 128 + ((lane >> 4) << 2);
#pragma unroll
  for (int mi = 0; mi < 8; ++mi)
#pragma unroll
    for (int n = 0; n < 4; ++n) {
      const size_t mb = m0 + mi * 16;
      const int nn = n0 + n * 16;
#pragma unroll
      for (int r = 0; r < 4; ++r) {
        const size_t idx = (mb + r) * (size_t)N + nn;
        const float v = acc[mi][n][r];
        if constexpr (EPI == 0) {
          Cf[idx] = v;
        } else {
          Cb[idx] = (bf16)v;
        }
      }
    }
}

// ---------------------------------------------------------------- LayerNorm (bf16 in/out)
__global__ __launch_bounds__(256) void k_ln(const bf16* __restrict__ X,
                                            const float* __restrict__ w,
                                            const float* __restrict__ bb,
                                            bf16* __restrict__ Yb) {
  const int m = blockIdx.x;
  const int tid = threadIdx.x;
  const bf16x4 v4 = *(const bf16x4*)(X + (size_t)m * DIMH + tid * 4);
  const float v0 = (float)v4[0], v1 = (float)v4[1], v2 = (float)v4[2], v3 = (float)v4[3];
  float s = v0 + v1 + v2 + v3;
  float s2 = v0 * v0 + v1 * v1 + v2 * v2 + v3 * v3;
#pragma unroll
  for (int off = 32; off > 0; off >>= 1) { s += __shfl_down(s, off); s2 += __shfl_down(s2, off); }
  __shared__ float rs[4], rq[4];
  if ((tid & 63) == 0) { rs[tid >> 6] = s; rq[tid >> 6] = s2; }
  __syncthreads();
  s = rs[0] + rs[1] + rs[2] + rs[3];
  s2 = rq[0] + rq[1] + rq[2] + rq[3];
  const float mu = s * (1.0f / DIMH);
  const float inv = rsqrtf(s2 * (1.0f / DIMH) - mu * mu + 1e-5f);
  const float4 wv = ((const float4*)w)[tid];
  const float4 bv = ((const float4*)bb)[tid];
  bf16x4 ob = { (bf16)((v0 - mu) * inv * wv.x + bv.x), (bf16)((v1 - mu) * inv * wv.y + bv.y),
                (bf16)((v2 - mu) * inv * wv.z + bv.z), (bf16)((v3 - mu) * inv * wv.w + bv.w) };
  *(bf16x4*)(Yb + (size_t)m * DIMH + tid * 4) = ob;
}

// fused: t = gelu(ys + D*fx) + fx ; LN(t) -> fx2, in-place into FXE
__global__ __launch_bounds__(256) void k_ln2e(const bf16* __restrict__ YS,
                                              bf16* FXE,
                                              const float* __restrict__ Dv,
                                              const float* __restrict__ w,
                                              const float* __restrict__ bb) {
  const int m = blockIdx.x;
  const int tid = threadIdx.x;
  const bf16x4 ys4 = *(const bf16x4*)(YS + (size_t)m * DIMH + tid * 4);
  const bf16x4 fx4 = *(const bf16x4*)(FXE + (size_t)m * DIMH + tid * 4);
  const float4 dv = ((const float4*)Dv)[tid];
  const float f0 = (float)fx4[0], f1 = (float)fx4[1], f2 = (float)fx4[2], f3 = (float)fx4[3];
  const float t0 = gelu_f((float)ys4[0] + dv.x * f0) + f0;
  const float t1 = gelu_f((float)ys4[1] + dv.y * f1) + f1;
  const float t2 = gelu_f((float)ys4[2] + dv.z * f2) + f2;
  const float t3 = gelu_f((float)ys4[3] + dv.w * f3) + f3;
  float s = t0 + t1 + t2 + t3;
  float s2 = t0 * t0 + t1 * t1 + t2 * t2 + t3 * t3;
#pragma unroll
  for (int off = 32; off > 0; off >>= 1) { s += __shfl_down(s, off); s2 += __shfl_down(s2, off); }
  __shared__ float rs[4], rq[4];
  if ((tid & 63) == 0) { rs[tid >> 6] = s; rq[tid >> 6] = s2; }
  __syncthreads();
  s = rs[0] + rs[1] + rs[2] + rs[3];
  s2 = rq[0] + rq[1] + rq[2] + rq[3];
  const float mu = s * (1.0f / DIMH);
  const float inv = rsqrtf(s2 * (1.0f / DIMH) - mu * mu + 1e-5f);
  const float4 wv = ((const float4*)w)[tid];
  const float4 bv = ((const float4*)bb)[tid];
  bf16x4 ob = { (bf16)((t0 - mu) * inv * wv.x + bv.x), (bf16)((t1 - mu) * inv * wv.y + bv.y),
                (bf16)((t2 - mu) * inv * wv.z + bv.z), (bf16)((t3 - mu) * inv * wv.w + bv.w) };
  *(bf16x4*)(FXE + (size_t)m * DIMH + tid * 4) = ob;
}

// ---------------------------------------------------------------- scan (3-pass, bf16 Bu)
__global__ __launch_bounds__(256) void k_scanA(const bf16* __restrict__ Bu,
                                               const float2* __restrict__ lamb,
                                               float2* __restrict__ carry) {
  const int bc = blockIdx.x;
  const int b = bc >> 8, c = bc & (NC - 1);
  const int t = threadIdx.x;
  const size_t rbase = ((size_t)b * LSEQ + (size_t)c * CL) * DIMH;
  float2 re[CL], im[CL];
#pragma unroll
  for (int i = 0; i < CL; ++i) {
    const bf16x2 r2 = *(const bf16x2*)(Bu + rbase + (size_t)i * DIMH + 2 * t);
    const bf16x2 i2 = *(const bf16x2*)(Bu + rbase + (size_t)i * DIMH + PDIM + 2 * t);
    re[i] = make_float2((float)r2[0], (float)r2[1]);
    im[i] = make_float2((float)i2[0], (float)i2[1]);
  }
  const float2 l0 = lamb[2 * t];
  const float2 l1 = lamb[2 * t + 1];
  const size_t cb = ((size_t)bc * 2) * PDIM;
  {
    float s0r = 0.f, s0i = 0.f, s1r = 0.f, s1i = 0.f;
#pragma unroll
    for (int i = 0; i < CL; ++i) {
      float nr = l0.x * s0r - l0.y * s0i + re[i].x;
      float ni = l0.x * s0i + l0.y * s0r + im[i].x;
      s0r = nr; s0i = ni;
      nr = l1.x * s1r - l1.y * s1i + re[i].y;
      ni = l1.x * s1i + l1.y * s1r + im[i].y;
      s1r = nr; s1i = ni;
    }
    carry[cb + 2 * t]     = make_float2(s0r, s0i);
    carry[cb + 2 * t + 1] = make_float2(s1r, s1i);
  }
  {
    float s0r = 0.f, s0i = 0.f, s1r = 0.f, s1i = 0.f;
#pragma unroll
    for (int i = CL - 1; i >= 0; --i) {
      float nr = l0.x * s0r - l0.y * s0i + re[i].x;
      float ni = l0.x * s0i + l0.y * s0r + im[i].x;
      s0r = nr; s0i = ni;
      nr = l1.x * s1r - l1.y * s1i + re[i].y;
      ni = l1.x * s1i + l1.y * s1r + im[i].y;
      s1r = nr; s1i = ni;
    }
    carry[cb + PDIM + 2 * t]     = make_float2(s0r, s0i);
    carry[cb + PDIM + 2 * t + 1] = make_float2(s1r, s1i);
  }
}

__global__ __launch_bounds__(256) void k_scanB(const float2* __restrict__ carry,
                                               const float2* __restrict__ lamb,
                                               float2* __restrict__ seed) {
  const int b = blockIdx.x;  // 4 blocks
  const int t = threadIdx.x;
  const float2 l0 = lamb[2 * t], l1 = lamb[2 * t + 1];
  float L0r = l0.x, L0i = l0.y, L1r = l1.x, L1i = l1.y;
#pragma unroll
  for (int q = 0; q < 4; ++q) {
    float tr = L0r * L0r - L0i * L0i; L0i = 2.f * L0r * L0i; L0r = tr;
    tr = L1r * L1r - L1i * L1i; L1i = 2.f * L1r * L1i; L1r = tr;
  }
  float S0r = 0.f, S0i = 0.f, S1r = 0.f, S1i = 0.f;
  for (int c = 0; c < NC; ++c) {
    const size_t base = (((size_t)b * NC + c) * 2) * PDIM;
    const float2 c0 = carry[base + 2 * t];
    const float2 c1 = carry[base + 2 * t + 1];
    seed[base + 2 * t]     = make_float2(S0r, S0i);
    seed[base + 2 * t + 1] = make_float2(S1r, S1i);
    float nr = L0r * S0r - L0i * S0i + c0.x;
    float ni = L0r * S0i + L0i * S0r + c0.y;
    S0r = nr; S0i = ni;
    nr = L1r * S1r - L1i * S1i + c1.x;
    ni = L1r * S1i + L1i * S1r + c1.y;
    S1r = nr; S1i = ni;
  }
  S0r = 0.f; S0i = 0.f; S1r = 0.f; S1i = 0.f;
  for (int c = NC - 1; c >= 0; --c) {
    const size_t base = (((size_t)b * NC + c) * 2) * PDIM + PDIM;
    const float2 c0 = carry[base + 2 * t];
    const float2 c1 = carry[base + 2 * t + 1];
    seed[base + 2 * t]     = make_float2(S0r, S0i);
    seed[base + 2 * t + 1] = make_float2(S1r, S1i);
    float nr = L0r * S0r - L0i * S0i + c0.x;
    float ni = L0r * S0i + L0i * S0r + c0.y;
    S0r = nr; S0i = ni;
    nr = L1r * S1r - L1i * S1i + c1.x;
    ni = L1r * S1i + L1i * S1r + c1.y;
    S1r = nr; S1i = ni;
  }
}

__global__ __launch_bounds__(256) void k_scanC(const bf16* __restrict__ Bu,
                                               const float2* __restrict__ lamb,
                                               const float2* __restrict__ seed,
                                               bf16* __restrict__ xs) {
  const int bc = blockIdx.x;
  const int b = bc >> 8, c = bc & (NC - 1);
  const int t = threadIdx.x;
  const size_t rbase = ((size_t)b * LSEQ + (size_t)c * CL) * DIMH;
  float2 re[CL], im[CL];
#pragma unroll
  for (int i = 0; i < CL; ++i) {
    const bf16x2 r2 = *(const bf16x2*)(Bu + rbase + (size_t)i * DIMH + 2 * t);
    const bf16x2 i2 = *(const bf16x2*)(Bu + rbase + (size_t)i * DIMH + PDIM + 2 * t);
    re[i] = make_float2((float)r2[0], (float)r2[1]);
    im[i] = make_float2((float)i2[0], (float)i2[1]);
  }
  const float2 l0 = lamb[2 * t];
  const float2 l1 = lamb[2 * t + 1];
  const size_t sb = ((size_t)bc * 2) * PDIM;
  const size_t obase = ((size_t)b * LSEQ + (size_t)c * CL) * 2048;
  {
    const float2 s0 = seed[sb + 2 * t];
    const float2 s1 = seed[sb + 2 * t + 1];
    float s0r = s0.x, s0i = s0.y, s1r = s1.x, s1i = s1.y;
#pragma unroll
    for (int i = 0; i < CL; ++i) {
      float nr = l0.x * s0r - l0.y * s0i + re[i].x;
      float ni = l0.x * s0i + l0.y * s0r + im[i].x;
      s0r = nr; s0i = ni;
      nr = l1.x * s1r - l1.y * s1i + re[i].y;
      ni = l1.x * s1i + l1.y * s1r + im[i].y;
      s1r = nr; s1i = ni;
      bf16x2 wr2 = { (bf16)s0r, (bf16)s1r };
      bf16x2 wi2 = { (bf16)s0i, (bf16)s1i };
      *(bf16x2*)(xs + obase + (size_t)i * 2048 + 2 * t) = wr2;
      *(bf16x2*)(xs + obase + (size_t)i * 2048 + PDIM + 2 * t) = wi2;
    }
  }
  {
    const float2 s0 = seed[sb + PDIM + 2 * t];
    const float2 s1 = seed[sb + PDIM + 2 * t + 1];
    float s0r = s0.x, s0i = s0.y, s1r = s1.x, s1i = s1.y;
#pragma unroll
    for (int i = CL - 1; i >= 0; --i) {
      float nr = l0.x * s0r - l0.y * s0i + re[i].x;
      float ni = l0.x * s0i + l0.y * s0r + im[i].x;
      s0r = nr; s0i = ni;
      nr = l1.x * s1r - l1.y * s1i + re[i].y;
      ni = l1.x * s1i + l1.y * s1r + im[i].y;
      s1r = nr; s1i = ni;
      bf16x2 wr2 = { (bf16)s0r, (bf16)s1r };
      bf16x2 wi2 = { (bf16)s0i, (bf16)s1i };
      *(bf16x2*)(xs + obase + (size_t)i * 2048 + 1024 + 2 * t) = wr2;
      *(bf16x2*)(xs + obase + (size_t)i * 2048 + 1536 + 2 * t) = wi2;
    }
  }
}

// ---------------------------------------------------------------- launch
extern "C" void kernel_launch(void* const* d_in, const int* in_sizes, int n_in,
                              void* d_out, int out_size, void* d_ws, size_t ws_size,
                              hipStream_t stream) {
  const float* x    = (const float*)d_in[0];
  const float* W_in = (const float*)d_in[1];
  const float* W_out= (const float*)d_in[2];
  const float* ln1w = (const float*)d_in[3];
  const float* ln1b = (const float*)d_in[4];
  const float* ln2w = (const float*)d_in[5];
  const float* ln2b = (const float*)d_in[6];
  const float* Lre  = (const float*)d_in[7];
  const float* Lim  = (const float*)d_in[8];
  const float* lstep= (const float*)d_in[9];
  const float* Bre  = (const float*)d_in[10];
  const float* Bim  = (const float*)d_in[11];
  const float* Cre  = (const float*)d_in[12];
  const float* Cim  = (const float*)d_in[13];
  const float* Dv   = (const float*)d_in[14];
  const float* ffe  = (const float*)d_in[15];
  const float* ffd  = (const float*)d_in[16];
  float* out = (float*)d_out;
  char* ws = (char*)d_ws;

  bf16* winb   = (bf16*)(ws);
  bf16* woutb  = (bf16*)(ws + (1u << 20));
  bf16* bcat   = (bf16*)(ws + (2u << 20));
  bf16* ccomb  = (bf16*)(ws + (4u << 20));
  bf16* ffeb   = (bf16*)(ws + (8u << 20));
  bf16* ffdb   = (bf16*)(ws + (12u << 20));
  float2* lamb = (float2*)(ws + (14u << 20));
  bf16* E      = (bf16*)(ws + (16u << 20));        // 32MB: x_b -> fx -> fx2
  bf16* hb     = (bf16*)(ws + (48u << 20));        // 32MB: h
  bf16* Bub    = (bf16*)(ws + (48u << 20));        // reuse (h dead after k_ln)
  bf16* ysb    = (bf16*)(ws + (48u << 20));        // reuse (Bu dead after scanC)
  bf16* x3b    = (bf16*)(ws + (48u << 20));        // reuse (ys dead after ln2e)
  bf16* xsb    = (bf16*)(ws + (80u << 20));        // 64MB: xs
  bf16* a_b    = (bf16*)(ws + (80u << 20));        // reuse (xs dead after C-proj)
  bf16* G      = (bf16*)(ws + (112u << 20));       // 32MB
  float2* carry = (float2*)(ws + (144u << 20));    // 8MB
  float2* seed  = (float2*)(ws + (152u << 20));    // 8MB

  static bool attr_done = false;
  if (!attr_done) {
    (void)hipFuncSetAttribute((const void*)&k_gemm<0>, hipFuncAttributeMaxDynamicSharedMemorySize, 49152);
    (void)hipFuncSetAttribute((const void*)&k_gemm<1>, hipFuncAttributeMaxDynamicSharedMemorySize, 49152);
    (void)hipFuncSetAttribute((const void*)&k_gemm<2>, hipFuncAttributeMaxDynamicSharedMemorySize, 49152);
    (void)hipFuncSetAttribute((const void*)&k_gemm<3>, hipFuncAttributeMaxDynamicSharedMemorySize, 49152);
    (void)hipFuncSetAttribute((const void*)&k_gemm2<3>, hipFuncAttributeMaxDynamicSharedMemorySize, 98304);
    attr_done = true;
  }

  // prep: one mega launch
  k_mega<<<14850, 256, 0, stream>>>(x, W_in, W_out, ffe, ffd, Lre, Lim, lstep,
                                    Bre, Bim, Cre, Cim,
                                    E, winb, woutb, ffeb, ffdb, bcat, ccomb, lamb);

  // h = x @ W_in^T -> hb (bf16)
  k_gemm<3><<<1024, 256, 49152, stream>>>(E, winb, nullptr, hb, nullptr, 512, 1024, 3);
  // fx = LN1(h) -> E (bf16)
  k_ln<<<16384, 256, 0, stream>>>(hb, ln1w, ln1b, E);
  // Bu = fx @ Bcat^T -> Bub (bf16)
  k_gemm<3><<<1024, 256, 49152, stream>>>(E, bcat, nullptr, Bub, nullptr, 1024, 1024, 3);
  // xs -> xsb (bf16) via 3-pass chunked scan
  k_scanA<<<4 * NC, 256, 0, stream>>>(Bub, lamb, carry);
  k_scanB<<<4, 256, 0, stream>>>(carry, lamb, seed);
  k_scanC<<<4 * NC, 256, 0, stream>>>(Bub, lamb, seed, xsb);
  // ys = xs @ Ccomb^T -> ysb (bf16): 256x256 3-buffer kernel (K=2048)
  k_gemm2<3><<<256, 512, 98304, stream>>>(xsb, ccomb, nullptr, ysb, 2048, 1024, 2);
  // x2 = gelu(ys + D*fx) + fx; fx2 = LN2(x2) -> E in place (bf16)
  k_ln2e<<<16384, 256, 0, stream>>>(ysb, E, Dv, ln2w, ln2b);
  // a-half -> a_b (bf16)
  k_gemm<3><<<1024, 256, 49152, stream>>>(E, ffeb, nullptr, a_b, nullptr, 1024, 1024, 3);
  // g-half + fused geglu -> G (bf16)
  k_gemm<1><<<1024, 256, 49152, stream>>>(E, ffeb + (size_t)1024 * 1024, nullptr, G, a_b, 1024, 1024, 3);
  // ffo + residual(fx2) -> x3b (bf16)
  k_gemm<2><<<1024, 256, 49152, stream>>>(G, ffdb, nullptr, x3b, E, 1024, 1024, 3);
  // out = x3 @ W_out^T (f32)
  k_gemm<0><<<512, 256, 49152, stream>>>(x3b, woutb, out, nullptr, nullptr, 1024, 512, 2);
}

// Round 17
// 447.602 us; speedup vs baseline: 1.0401x; 1.0010x over previous
//
#include <hip/hip_runtime.h>
#include <cstdint>

typedef __bf16 bf16;
typedef __bf16 bf16x2 __attribute__((ext_vector_type(2)));
typedef __bf16 bf16x4 __attribute__((ext_vector_type(4)));
typedef __bf16 bf16x8 __attribute__((ext_vector_type(8)));
typedef float f32x4 __attribute__((ext_vector_type(4)));

#define MROWS 16384
#define DIMH 1024
#define PDIM 512
#define LSEQ 4096
#define CL 16
#define NC (LSEQ / CL)  // 256

typedef const __attribute__((address_space(1))) unsigned int* gas_t;
typedef __attribute__((address_space(3))) unsigned int* las_t;

__device__ __forceinline__ float gelu_f(float x) {
  return 0.5f * x * (1.0f + erff(x * 0.70710678118654752f));
}

// ---------------------------------------------------------------- mega prep
__global__ __launch_bounds__(256) void k_mega(
    const float* __restrict__ x, const float* __restrict__ W_in,
    const float* __restrict__ W_out, const float* __restrict__ ffe,
    const float* __restrict__ ffd, const float* __restrict__ Lre,
    const float* __restrict__ Lim, const float* __restrict__ lstep,
    const float* __restrict__ Bre, const float* __restrict__ Bim,
    const float* __restrict__ Cre, const float* __restrict__ Cim,
    bf16* __restrict__ xb, bf16* __restrict__ winb, bf16* __restrict__ woutb,
    bf16* __restrict__ ffeb, bf16* __restrict__ ffdb, bf16* __restrict__ bcat,
    bf16* __restrict__ cc, float2* __restrict__ lamb) {
  const int bid = blockIdx.x;
  const int tid = threadIdx.x;
  auto cvt4 = [&](const float* src, bf16* dst, int i4) {
    const float4 v = *(const float4*)(src + i4);
    bf16x4 o = { (bf16)v.x, (bf16)v.y, (bf16)v.z, (bf16)v.w };
    *(bf16x4*)(dst + i4) = o;
  };
  if (bid < 8192) {
    cvt4(x, xb, bid * 1024 + tid * 4);
  } else if (bid < 8704) {
    cvt4(W_in, winb, (bid - 8192) * 1024 + tid * 4);
  } else if (bid < 9216) {
    cvt4(W_out, woutb, (bid - 8704) * 1024 + tid * 4);
  } else if (bid < 11264) {
    cvt4(ffe, ffeb, (bid - 9216) * 1024 + tid * 4);
  } else if (bid < 12288) {
    cvt4(ffd, ffdb, (bid - 11264) * 1024 + tid * 4);
  } else if (bid < 12800) {
    const int i4 = (bid - 12288) * 1024 + tid * 4;
    const int p = i4 >> 10;
    const float lre = Lre[p], lim = Lim[p];
    const float st = expf(lstep[p]);
    const float er = expf(lre * st);
    const float lbr = er * cosf(lim * st);
    const float lbi = er * sinf(lim * st);
    const float ar = lbr - 1.0f, ai = lbi;
    const float d = lre * lre + lim * lim;
    const float cx = (ar * lre + ai * lim) / d;
    const float cy = (ai * lre - ar * lim) / d;
    const float4 br = *(const float4*)(Bre + i4);
    const float4 bi = *(const float4*)(Bim + i4);
    bf16x4 o1 = { (bf16)(cx * br.x - cy * bi.x), (bf16)(cx * br.y - cy * bi.y),
                  (bf16)(cx * br.z - cy * bi.z), (bf16)(cx * br.w - cy * bi.w) };
    bf16x4 o2 = { (bf16)(cx * bi.x + cy * br.x), (bf16)(cx * bi.y + cy * br.y),
                  (bf16)(cx * bi.z + cy * br.z), (bf16)(cx * bi.w + cy * br.w) };
    *(bf16x4*)(bcat + i4) = o1;
    *(bf16x4*)(bcat + i4 + PDIM * DIMH) = o2;
  } else if (bid < 14848) {
    const int i4 = (bid - 12800) * 1024 + tid * 4;
    const int n = i4 >> 11, k0 = i4 & 2047;
    const float* src;
    float sgn;
    int kk;
    if (k0 < 512)       { src = Cre + n * 1024;       sgn =  2.0f; kk = k0; }
    else if (k0 < 1024) { src = Cim + n * 1024;       sgn = -2.0f; kk = k0 - 512; }
    else if (k0 < 1536) { src = Cre + n * 1024 + 512; sgn =  2.0f; kk = k0 - 1024; }
    else                { src = Cim + n * 1024 + 512; sgn = -2.0f; kk = k0 - 1536; }
    const float4 v = *(const float4*)(src + kk);
    bf16x4 o = { (bf16)(sgn * v.x), (bf16)(sgn * v.y), (bf16)(sgn * v.z), (bf16)(sgn * v.w) };
    *(bf16x4*)(cc + i4) = o;
  } else {
    const int p = (bid - 14848) * 256 + tid;
    if (p < PDIM) {
      const float lre = Lre[p], lim = Lim[p];
      const float st = expf(lstep[p]);
      const float er = expf(lre * st);
      lamb[p] = make_float2(er * cosf(lim * st), er * sinf(lim * st));
    }
  }
}

#define VMCNT4 asm volatile("s_waitcnt vmcnt(4)" ::: "memory")
#define VMCNT0 asm volatile("s_waitcnt vmcnt(0)" ::: "memory")
#define LGKM0  asm volatile("s_waitcnt lgkmcnt(0)" ::: "memory")
#define SCHED0 __builtin_amdgcn_sched_barrier(0)
#define BAR    __builtin_amdgcn_s_barrier()

// ---------------------------------------------------------------- GEMM A (128x128, 3-buffer, 1 barrier/unit, 3 blocks/CU)
// EPI: 0 = f32 store; 1 = bf16(auxb * gelu(acc)); 2 = bf16(acc + auxb); 3 = bf16.
// EPI 1/2 use an LDS-staged coalesced epilogue.  Epilogue barriers are
// __syncthreads() (fenced) — raw s_barrier raced (lgkm not drained, R16).
template <int EPI>
__global__ __launch_bounds__(256, 3) void k_gemm(const bf16* __restrict__ A,
                                                 const bf16* __restrict__ W,
                                                 float* __restrict__ Cf,
                                                 bf16* __restrict__ Cb,
                                                 const bf16* __restrict__ auxb,
                                                 int K, int N, int nbnl) {
  extern __shared__ char lds[];  // 49152 bytes: 3 x (A 8KB + B 8KB)
  const int q = (int)gridDim.x >> 3;
  const int s = ((int)blockIdx.x & 7) * q + ((int)blockIdx.x >> 3);
  const int bm = s >> nbnl;
  const int bn = s & ((1 << nbnl) - 1);
  const int tid = threadIdx.x;
  const int lane = tid & 63;
  const int wave = tid >> 6;   // 0..3
  const int wr = wave >> 1;    // 0..1
  const int wc = wave & 1;     // 0..1

  const size_t arow0 = (size_t)bm * 128;
  const size_t wrow0 = (size_t)bn * 128;
  const int srow = tid >> 2;                         // 0..63 per issue
  const int schunk = (tid & 3) ^ ((tid >> 3) & 3);   // inverse-swizzled src chunk
  const int wbase = wave << 10;

  f32x4 acc[4][4];
#pragma unroll
  for (int i = 0; i < 4; ++i)
#pragma unroll
    for (int j = 0; j < 4; ++j) acc[i][j] = (f32x4){0.f, 0.f, 0.f, 0.f};

  auto stage = [&](int buf, int ui) {
    const int kcol = ui * 32 + schunk * 8;
    char* ba = lds + buf * 16384;
    __builtin_amdgcn_global_load_lds(
        (gas_t)(A + (arow0 + srow) * (size_t)K + kcol), (las_t)(ba + wbase), 16, 0, 0);
    __builtin_amdgcn_global_load_lds(
        (gas_t)(A + (arow0 + 64 + srow) * (size_t)K + kcol), (las_t)(ba + 4096 + wbase), 16, 0, 0);
    char* bb = ba + 8192;
    __builtin_amdgcn_global_load_lds(
        (gas_t)(W + (wrow0 + srow) * (size_t)K + kcol), (las_t)(bb + wbase), 16, 0, 0);
    __builtin_amdgcn_global_load_lds(
        (gas_t)(W + (wrow0 + 64 + srow) * (size_t)K + kcol), (las_t)(bb + 4096 + wbase), 16, 0, 0);
  };

  auto ldA = [&](int buf, bf16x8* af) {
#pragma unroll
    for (int m = 0; m < 4; ++m) {
      const int row = wr * 64 + m * 16 + (lane & 15);
      const int pc = (lane >> 4) ^ ((row >> 1) & 3);
      af[m] = *(const bf16x8*)(lds + buf * 16384 + row * 64 + pc * 16);
    }
  };
  auto ldB = [&](int buf, bf16x8* bf) {
#pragma unroll
    for (int n = 0; n < 4; ++n) {
      const int row = wc * 64 + n * 16 + (lane & 15);
      const int pc = (lane >> 4) ^ ((row >> 1) & 3);
      bf[n] = *(const bf16x8*)(lds + buf * 16384 + 8192 + row * 64 + pc * 16);
    }
  };

  bf16x8 afr[4], bfr[4];

  stage(0, 0);
  stage(1, 1);
  VMCNT4;
  BAR;

  const int NU = K >> 5;  // units of 32 K-cols
  int buf = 0, sbuf = 2;
  for (int u = 0; u < NU; ++u) {
    ldB(buf, bfr);
    ldA(buf, afr);
    if (u + 2 < NU) stage(sbuf, u + 2);
    LGKM0; SCHED0;
    __builtin_amdgcn_s_setprio(1);
#pragma unroll
    for (int m = 0; m < 4; ++m)
#pragma unroll
      for (int n = 0; n < 4; ++n)
        acc[m][n] = __builtin_amdgcn_mfma_f32_16x16x32_bf16(afr[m], bfr[n], acc[m][n], 0, 0, 0);
    __builtin_amdgcn_s_setprio(0);
    SCHED0;
    if (u + 2 < NU) { VMCNT4; }
    else if (u + 1 < NU) { VMCNT0; }
    BAR;
    buf = (buf == 2) ? 0 : buf + 1;
    sbuf = (sbuf == 2) ? 0 : sbuf + 1;
  }

  if constexpr (EPI == 1 || EPI == 2) {
    // LDS-staged coalesced epilogue.  All barriers fenced (__syncthreads).
    float* sml = (float*)lds;
    __syncthreads();  // all waves' final frag reads retired before overwrite
#pragma unroll
    for (int h = 0; h < 2; ++h) {
      if (wr == h) {
#pragma unroll
        for (int mi = 0; mi < 4; ++mi)
#pragma unroll
          for (int n = 0; n < 4; ++n) {
            const int lrow0 = mi * 16 + ((lane >> 4) << 2);
            const int lcol = wc * 64 + (lane & 15) + n * 16;
#pragma unroll
            for (int r = 0; r < 4; ++r)
              sml[(lrow0 + r) * 132 + lcol] = acc[mi][n][r];
          }
      }
      __syncthreads();
      const int lrow = tid >> 2;
      const int c0 = (tid & 3) * 32;
      const size_t goff = (arow0 + h * 64 + lrow) * (size_t)N + wrow0 + c0;
      const float* sp = sml + lrow * 132 + c0;
#pragma unroll
      for (int j = 0; j < 4; ++j) {
        const bf16x8 a8 = *(const bf16x8*)(auxb + goff + j * 8);
        bf16x8 o8;
#pragma unroll
        for (int e = 0; e < 8; ++e) {
          const float v = sp[j * 8 + e];
          if constexpr (EPI == 1) o8[e] = (bf16)((float)a8[e] * gelu_f(v));
          else                    o8[e] = (bf16)(v + (float)a8[e]);
        }
        *(bf16x8*)(Cb + goff + j * 8) = o8;
      }
      if (h == 0) __syncthreads();  // half-0 reads done before half-1 writes
    }
  } else {
    const int n0 = (int)wrow0 + wc * 64 + (lane & 15);
    const size_t m0 = arow0 + wr * 64 + ((lane >> 4) << 2);
#pragma unroll
    for (int mi = 0; mi < 4; ++mi)
#pragma unroll
      for (int n = 0; n < 4; ++n) {
        const size_t mb = m0 + mi * 16;
        const int nn = n0 + n * 16;
#pragma unroll
        for (int r = 0; r < 4; ++r) {
          const size_t idx = (mb + r) * (size_t)N + nn;
          const float v = acc[mi][n][r];
          if constexpr (EPI == 0) {
            Cf[idx] = v;
          } else {
            Cb[idx] = (bf16)v;
          }
        }
      }
  }
}

// ---------------------------------------------------------------- GEMM B (256x256, 3-buffer rotation, 1 barrier/unit)
// For K=2048 (C-proj). unit = 32 K-cols, LDS 3 x (A 16KB + B 16KB) = 96 KB.
template <int EPI>
__global__ __launch_bounds__(512, 1) void k_gemm2(const bf16* __restrict__ A,
                                                  const bf16* __restrict__ W,
                                                  float* __restrict__ Cf,
                                                  bf16* __restrict__ Cb,
                                                  int K, int N, int nbnl) {
  extern __shared__ char lds[];  // 98304 bytes
  const int q = (int)gridDim.x >> 3;
  const int s = ((int)blockIdx.x & 7) * q + ((int)blockIdx.x >> 3);
  const int bm = s >> nbnl;
  const int bn = s & ((1 << nbnl) - 1);
  const int tid = threadIdx.x;
  const int lane = tid & 63;
  const int wave = tid >> 6;
  const int wr = wave >> 2;  // 0..1
  const int wc = wave & 3;   // 0..3

  const size_t arow0 = (size_t)bm * 256;
  const size_t wrow0 = (size_t)bn * 256;
  const int srow = tid >> 2;                         // 0..127 per issue
  const int schunk = (tid & 3) ^ ((tid >> 3) & 3);
  const int wbase = wave << 10;

  f32x4 acc[8][4];
#pragma unroll
  for (int i = 0; i < 8; ++i)
#pragma unroll
    for (int j = 0; j < 4; ++j) acc[i][j] = (f32x4){0.f, 0.f, 0.f, 0.f};

  auto stage = [&](int buf, int ui) {
    const int kcol = ui * 32 + schunk * 8;
    char* ba = lds + buf * 32768;
    __builtin_amdgcn_global_load_lds(
        (gas_t)(A + (arow0 + srow) * (size_t)K + kcol), (las_t)(ba + wbase), 16, 0, 0);
    __builtin_amdgcn_global_load_lds(
        (gas_t)(A + (arow0 + 128 + srow) * (size_t)K + kcol), (las_t)(ba + 8192 + wbase), 16, 0, 0);
    char* bb = ba + 16384;
    __builtin_amdgcn_global_load_lds(
        (gas_t)(W + (wrow0 + srow) * (size_t)K + kcol), (las_t)(bb + wbase), 16, 0, 0);
    __builtin_amdgcn_global_load_lds(
        (gas_t)(W + (wrow0 + 128 + srow) * (size_t)K + kcol), (las_t)(bb + 8192 + wbase), 16, 0, 0);
  };

  auto ldA = [&](int buf, bf16x8* af) {
#pragma unroll
    for (int m = 0; m < 8; ++m) {
      const int row = wr * 128 + m * 16 + (lane & 15);
      const int pc = (lane >> 4) ^ ((row >> 1) & 3);
      af[m] = *(const bf16x8*)(lds + buf * 32768 + row * 64 + pc * 16);
    }
  };
  auto ldB = [&](int buf, bf16x8* bf) {
#pragma unroll
    for (int n = 0; n < 4; ++n) {
      const int row = wc * 64 + n * 16 + (lane & 15);
      const int pc = (lane >> 4) ^ ((row >> 1) & 3);
      bf[n] = *(const bf16x8*)(lds + buf * 32768 + 16384 + row * 64 + pc * 16);
    }
  };

  bf16x8 afr[8], bfr[4];

  stage(0, 0);
  stage(1, 1);
  VMCNT4;
  BAR;

  const int NU = K >> 5;  // 64 units for K=2048
  int buf = 0, sbuf = 2;
  for (int u = 0; u < NU; ++u) {
    ldB(buf, bfr);
    ldA(buf, afr);
    if (u + 2 < NU) stage(sbuf, u + 2);
    LGKM0; SCHED0;
    __builtin_amdgcn_s_setprio(1);
#pragma unroll
    for (int m = 0; m < 8; ++m)
#pragma unroll
      for (int n = 0; n < 4; ++n)
        acc[m][n] = __builtin_amdgcn_mfma_f32_16x16x32_bf16(afr[m], bfr[n], acc[m][n], 0, 0, 0);
    __builtin_amdgcn_s_setprio(0);
    SCHED0;
    if (u + 2 < NU) { VMCNT4; }
    else if (u + 1 < NU) { VMCNT0; }
    BAR;
    buf = (buf == 2) ? 0 : buf + 1;
    sbuf = (sbuf == 2) ? 0 : sbuf + 1;
  }

  const int n0 = (int)wrow0 + wc * 64 + (lane & 15);
  const size_t m0 = arow0 + wr * 128 + ((lane >> 4) << 2);
#pragma unroll
  for (int mi = 0; mi < 8; ++mi)
#pragma unroll
    for (int n = 0; n < 4; ++n) {
      const size_t mb = m0 + mi * 16;
      const int nn = n0 + n * 16;
#pragma unroll
      for (int r = 0; r < 4; ++r) {
        const size_t idx = (mb + r) * (size_t)N + nn;
        const float v = acc[mi][n][r];
        if constexpr (EPI == 0) {
          Cf[idx] = v;
        } else {
          Cb[idx] = (bf16)v;
        }
      }
    }
}

// ---------------------------------------------------------------- LayerNorm (bf16 in/out)
__global__ __launch_bounds__(256) void k_ln(const bf16* __restrict__ X,
                                            const float* __restrict__ w,
                                            const float* __restrict__ bb,
                                            bf16* __restrict__ Yb) {
  const int m = blockIdx.x;
  const int tid = threadIdx.x;
  const bf16x4 v4 = *(const bf16x4*)(X + (size_t)m * DIMH + tid * 4);
  const float v0 = (float)v4[0], v1 = (float)v4[1], v2 = (float)v4[2], v3 = (float)v4[3];
  float s = v0 + v1 + v2 + v3;
  float s2 = v0 * v0 + v1 * v1 + v2 * v2 + v3 * v3;
#pragma unroll
  for (int off = 32; off > 0; off >>= 1) { s += __shfl_down(s, off); s2 += __shfl_down(s2, off); }
  __shared__ float rs[4], rq[4];
  if ((tid & 63) == 0) { rs[tid >> 6] = s; rq[tid >> 6] = s2; }
  __syncthreads();
  s = rs[0] + rs[1] + rs[2] + rs[3];
  s2 = rq[0] + rq[1] + rq[2] + rq[3];
  const float mu = s * (1.0f / DIMH);
  const float inv = rsqrtf(s2 * (1.0f / DIMH) - mu * mu + 1e-5f);
  const float4 wv = ((const float4*)w)[tid];
  const float4 bv = ((const float4*)bb)[tid];
  bf16x4 ob = { (bf16)((v0 - mu) * inv * wv.x + bv.x), (bf16)((v1 - mu) * inv * wv.y + bv.y),
                (bf16)((v2 - mu) * inv * wv.z + bv.z), (bf16)((v3 - mu) * inv * wv.w + bv.w) };
  *(bf16x4*)(Yb + (size_t)m * DIMH + tid * 4) = ob;
}

// fused: t = gelu(ys + D*fx) + fx ; LN(t) -> fx2, in-place into FXE
__global__ __launch_bounds__(256) void k_ln2e(const bf16* __restrict__ YS,
                                              bf16* FXE,
                                              const float* __restrict__ Dv,
                                              const float* __restrict__ w,
                                              const float* __restrict__ bb) {
  const int m = blockIdx.x;
  const int tid = threadIdx.x;
  const bf16x4 ys4 = *(const bf16x4*)(YS + (size_t)m * DIMH + tid * 4);
  const bf16x4 fx4 = *(const bf16x4*)(FXE + (size_t)m * DIMH + tid * 4);
  const float4 dv = ((const float4*)Dv)[tid];
  const float f0 = (float)fx4[0], f1 = (float)fx4[1], f2 = (float)fx4[2], f3 = (float)fx4[3];
  const float t0 = gelu_f((float)ys4[0] + dv.x * f0) + f0;
  const float t1 = gelu_f((float)ys4[1] + dv.y * f1) + f1;
  const float t2 = gelu_f((float)ys4[2] + dv.z * f2) + f2;
  const float t3 = gelu_f((float)ys4[3] + dv.w * f3) + f3;
  float s = t0 + t1 + t2 + t3;
  float s2 = t0 * t0 + t1 * t1 + t2 * t2 + t3 * t3;
#pragma unroll
  for (int off = 32; off > 0; off >>= 1) { s += __shfl_down(s, off); s2 += __shfl_down(s2, off); }
  __shared__ float rs[4], rq[4];
  if ((tid & 63) == 0) { rs[tid >> 6] = s; rq[tid >> 6] = s2; }
  __syncthreads();
  s = rs[0] + rs[1] + rs[2] + rs[3];
  s2 = rq[0] + rq[1] + rq[2] + rq[3];
  const float mu = s * (1.0f / DIMH);
  const float inv = rsqrtf(s2 * (1.0f / DIMH) - mu * mu + 1e-5f);
  const float4 wv = ((const float4*)w)[tid];
  const float4 bv = ((const float4*)bb)[tid];
  bf16x4 ob = { (bf16)((t0 - mu) * inv * wv.x + bv.x), (bf16)((t1 - mu) * inv * wv.y + bv.y),
                (bf16)((t2 - mu) * inv * wv.z + bv.z), (bf16)((t3 - mu) * inv * wv.w + bv.w) };
  *(bf16x4*)(FXE + (size_t)m * DIMH + tid * 4) = ob;
}

// ---------------------------------------------------------------- scan (3-pass, bf16 Bu)
__global__ __launch_bounds__(256) void k_scanA(const bf16* __restrict__ Bu,
                                               const float2* __restrict__ lamb,
                                               float2* __restrict__ carry) {
  const int bc = blockIdx.x;
  const int b = bc >> 8, c = bc & (NC - 1);
  const int t = threadIdx.x;
  const size_t rbase = ((size_t)b * LSEQ + (size_t)c * CL) * DIMH;
  float2 re[CL], im[CL];
#pragma unroll
  for (int i = 0; i < CL; ++i) {
    const bf16x2 r2 = *(const bf16x2*)(Bu + rbase + (size_t)i * DIMH + 2 * t);
    const bf16x2 i2 = *(const bf16x2*)(Bu + rbase + (size_t)i * DIMH + PDIM + 2 * t);
    re[i] = make_float2((float)r2[0], (float)r2[1]);
    im[i] = make_float2((float)i2[0], (float)i2[1]);
  }
  const float2 l0 = lamb[2 * t];
  const float2 l1 = lamb[2 * t + 1];
  const size_t cb = ((size_t)bc * 2) * PDIM;
  {
    float s0r = 0.f, s0i = 0.f, s1r = 0.f, s1i = 0.f;
#pragma unroll
    for (int i = 0; i < CL; ++i) {
      float nr = l0.x * s0r - l0.y * s0i + re[i].x;
      float ni = l0.x * s0i + l0.y * s0r + im[i].x;
      s0r = nr; s0i = ni;
      nr = l1.x * s1r - l1.y * s1i + re[i].y;
      ni = l1.x * s1i + l1.y * s1r + im[i].y;
      s1r = nr; s1i = ni;
    }
    carry[cb + 2 * t]     = make_float2(s0r, s0i);
    carry[cb + 2 * t + 1] = make_float2(s1r, s1i);
  }
  {
    float s0r = 0.f, s0i = 0.f, s1r = 0.f, s1i = 0.f;
#pragma unroll
    for (int i = CL - 1; i >= 0; --i) {
      float nr = l0.x * s0r - l0.y * s0i + re[i].x;
      float ni = l0.x * s0i + l0.y * s0r + im[i].x;
      s0r = nr; s0i = ni;
      nr = l1.x * s1r - l1.y * s1i + re[i].y;
      ni = l1.x * s1i + l1.y * s1r + im[i].y;
      s1r = nr; s1i = ni;
    }
    carry[cb + PDIM + 2 * t]     = make_float2(s0r, s0i);
    carry[cb + PDIM + 2 * t + 1] = make_float2(s1r, s1i);
  }
}

__global__ __launch_bounds__(256) void k_scanB(const float2* __restrict__ carry,
                                               const float2* __restrict__ lamb,
                                               float2* __restrict__ seed) {
  const int b = blockIdx.x;  // 4 blocks
  const int t = threadIdx.x;
  const float2 l0 = lamb[2 * t], l1 = lamb[2 * t + 1];
  float L0r = l0.x, L0i = l0.y, L1r = l1.x, L1i = l1.y;
#pragma unroll
  for (int q = 0; q < 4; ++q) {
    float tr = L0r * L0r - L0i * L0i; L0i = 2.f * L0r * L0i; L0r = tr;
    tr = L1r * L1r - L1i * L1i; L1i = 2.f * L1r * L1i; L1r = tr;
  }
  float S0r = 0.f, S0i = 0.f, S1r = 0.f, S1i = 0.f;
  for (int c = 0; c < NC; ++c) {
    const size_t base = (((size_t)b * NC + c) * 2) * PDIM;
    const float2 c0 = carry[base + 2 * t];
    const float2 c1 = carry[base + 2 * t + 1];
    seed[base + 2 * t]     = make_float2(S0r, S0i);
    seed[base + 2 * t + 1] = make_float2(S1r, S1i);
    float nr = L0r * S0r - L0i * S0i + c0.x;
    float ni = L0r * S0i + L0i * S0r + c0.y;
    S0r = nr; S0i = ni;
    nr = L1r * S1r - L1i * S1i + c1.x;
    ni = L1r * S1i + L1i * S1r + c1.y;
    S1r = nr; S1i = ni;
  }
  S0r = 0.f; S0i = 0.f; S1r = 0.f; S1i = 0.f;
  for (int c = NC - 1; c >= 0; --c) {
    const size_t base = (((size_t)b * NC + c) * 2) * PDIM + PDIM;
    const float2 c0 = carry[base + 2 * t];
    const float2 c1 = carry[base + 2 * t + 1];
    seed[base + 2 * t]     = make_float2(S0r, S0i);
    seed[base + 2 * t + 1] = make_float2(S1r, S1i);
    float nr = L0r * S0r - L0i * S0i + c0.x;
    float ni = L0r * S0i + L0i * S0r + c0.y;
    S0r = nr; S0i = ni;
    nr = L1r * S1r - L1i * S1i + c1.x;
    ni = L1r * S1i + L1i * S1r + c1.y;
    S1r = nr; S1i = ni;
  }
}

__global__ __launch_bounds__(256) void k_scanC(const bf16* __restrict__ Bu,
                                               const float2* __restrict__ lamb,
                                               const float2* __restrict__ seed,
                                               bf16* __restrict__ xs) {
  const int bc = blockIdx.x;
  const int b = bc >> 8, c = bc & (NC - 1);
  const int t = threadIdx.x;
  const size_t rbase = ((size_t)b * LSEQ + (size_t)c * CL) * DIMH;
  float2 re[CL], im[CL];
#pragma unroll
  for (int i = 0; i < CL; ++i) {
    const bf16x2 r2 = *(const bf16x2*)(Bu + rbase + (size_t)i * DIMH + 2 * t);
    const bf16x2 i2 = *(const bf16x2*)(Bu + rbase + (size_t)i * DIMH + PDIM + 2 * t);
    re[i] = make_float2((float)r2[0], (float)r2[1]);
    im[i] = make_float2((float)i2[0], (float)i2[1]);
  }
  const float2 l0 = lamb[2 * t];
  const float2 l1 = lamb[2 * t + 1];
  const size_t sb = ((size_t)bc * 2) * PDIM;
  const size_t obase = ((size_t)b * LSEQ + (size_t)c * CL) * 2048;
  {
    const float2 s0 = seed[sb + 2 * t];
    const float2 s1 = seed[sb + 2 * t + 1];
    float s0r = s0.x, s0i = s0.y, s1r = s1.x, s1i = s1.y;
#pragma unroll
    for (int i = 0; i < CL; ++i) {
      float nr = l0.x * s0r - l0.y * s0i + re[i].x;
      float ni = l0.x * s0i + l0.y * s0r + im[i].x;
      s0r = nr; s0i = ni;
      nr = l1.x * s1r - l1.y * s1i + re[i].y;
      ni = l1.x * s1i + l1.y * s1r + im[i].y;
      s1r = nr; s1i = ni;
      bf16x2 wr2 = { (bf16)s0r, (bf16)s1r };
      bf16x2 wi2 = { (bf16)s0i, (bf16)s1i };
      *(bf16x2*)(xs + obase + (size_t)i * 2048 + 2 * t) = wr2;
      *(bf16x2*)(xs + obase + (size_t)i * 2048 + PDIM + 2 * t) = wi2;
    }
  }
  {
    const float2 s0 = seed[sb + PDIM + 2 * t];
    const float2 s1 = seed[sb + PDIM + 2 * t + 1];
    float s0r = s0.x, s0i = s0.y, s1r = s1.x, s1i = s1.y;
#pragma unroll
    for (int i = CL - 1; i >= 0; --i) {
      float nr = l0.x * s0r - l0.y * s0i + re[i].x;
      float ni = l0.x * s0i + l0.y * s0r + im[i].x;
      s0r = nr; s0i = ni;
      nr = l1.x * s1r - l1.y * s1i + re[i].y;
      ni = l1.x * s1i + l1.y * s1r + im[i].y;
      s1r = nr; s1i = ni;
      bf16x2 wr2 = { (bf16)s0r, (bf16)s1r };
      bf16x2 wi2 = { (bf16)s0i, (bf16)s1i };
      *(bf16x2*)(xs + obase + (size_t)i * 2048 + 1024 + 2 * t) = wr2;
      *(bf16x2*)(xs + obase + (size_t)i * 2048 + 1536 + 2 * t) = wi2;
    }
  }
}

// ---------------------------------------------------------------- launch
extern "C" void kernel_launch(void* const* d_in, const int* in_sizes, int n_in,
                              void* d_out, int out_size, void* d_ws, size_t ws_size,
                              hipStream_t stream) {
  const float* x    = (const float*)d_in[0];
  const float* W_in = (const float*)d_in[1];
  const float* W_out= (const float*)d_in[2];
  const float* ln1w = (const float*)d_in[3];
  const float* ln1b = (const float*)d_in[4];
  const float* ln2w = (const float*)d_in[5];
  const float* ln2b = (const float*)d_in[6];
  const float* Lre  = (const float*)d_in[7];
  const float* Lim  = (const float*)d_in[8];
  const float* lstep= (const float*)d_in[9];
  const float* Bre  = (const float*)d_in[10];
  const float* Bim  = (const float*)d_in[11];
  const float* Cre  = (const float*)d_in[12];
  const float* Cim  = (const float*)d_in[13];
  const float* Dv   = (const float*)d_in[14];
  const float* ffe  = (const float*)d_in[15];
  const float* ffd  = (const float*)d_in[16];
  float* out = (float*)d_out;
  char* ws = (char*)d_ws;

  bf16* winb   = (bf16*)(ws);
  bf16* woutb  = (bf16*)(ws + (1u << 20));
  bf16* bcat   = (bf16*)(ws + (2u << 20));
  bf16* ccomb  = (bf16*)(ws + (4u << 20));
  bf16* ffeb   = (bf16*)(ws + (8u << 20));
  bf16* ffdb   = (bf16*)(ws + (12u << 20));
  float2* lamb = (float2*)(ws + (14u << 20));
  bf16* E      = (bf16*)(ws + (16u << 20));        // 32MB: x_b -> fx -> fx2
  bf16* hb     = (bf16*)(ws + (48u << 20));        // 32MB: h
  bf16* Bub    = (bf16*)(ws + (48u << 20));        // reuse (h dead after k_ln)
  bf16* ysb    = (bf16*)(ws + (48u << 20));        // reuse (Bu dead after scanC)
  bf16* x3b    = (bf16*)(ws + (48u << 20));        // reuse (ys dead after ln2e)
  bf16* xsb    = (bf16*)(ws + (80u << 20));        // 64MB: xs
  bf16* a_b    = (bf16*)(ws + (80u << 20));        // reuse (xs dead after C-proj)
  bf16* G      = (bf16*)(ws + (112u << 20));       // 32MB
  float2* carry = (float2*)(ws + (144u << 20));    // 8MB
  float2* seed  = (float2*)(ws + (152u << 20));    // 8MB

  static bool attr_done = false;
  if (!attr_done) {
    (void)hipFuncSetAttribute((const void*)&k_gemm<0>, hipFuncAttributeMaxDynamicSharedMemorySize, 49152);
    (void)hipFuncSetAttribute((const void*)&k_gemm<1>, hipFuncAttributeMaxDynamicSharedMemorySize, 49152);
    (void)hipFuncSetAttribute((const void*)&k_gemm<2>, hipFuncAttributeMaxDynamicSharedMemorySize, 49152);
    (void)hipFuncSetAttribute((const void*)&k_gemm<3>, hipFuncAttributeMaxDynamicSharedMemorySize, 49152);
    (void)hipFuncSetAttribute((const void*)&k_gemm2<3>, hipFuncAttributeMaxDynamicSharedMemorySize, 98304);
    attr_done = true;
  }

  // prep: one mega launch
  k_mega<<<14850, 256, 0, stream>>>(x, W_in, W_out, ffe, ffd, Lre, Lim, lstep,
                                    Bre, Bim, Cre, Cim,
                                    E, winb, woutb, ffeb, ffdb, bcat, ccomb, lamb);

  // h = x @ W_in^T -> hb (bf16)
  k_gemm<3><<<1024, 256, 49152, stream>>>(E, winb, nullptr, hb, nullptr, 512, 1024, 3);
  // fx = LN1(h) -> E (bf16)
  k_ln<<<16384, 256, 0, stream>>>(hb, ln1w, ln1b, E);
  // Bu = fx @ Bcat^T -> Bub (bf16)
  k_gemm<3><<<1024, 256, 49152, stream>>>(E, bcat, nullptr, Bub, nullptr, 1024, 1024, 3);
  // xs -> xsb (bf16) via 3-pass chunked scan
  k_scanA<<<4 * NC, 256, 0, stream>>>(Bub, lamb, carry);
  k_scanB<<<4, 256, 0, stream>>>(carry, lamb, seed);
  k_scanC<<<4 * NC, 256, 0, stream>>>(Bub, lamb, seed, xsb);
  // ys = xs @ Ccomb^T -> ysb (bf16): 256x256 3-buffer kernel (K=2048)
  k_gemm2<3><<<256, 512, 98304, stream>>>(xsb, ccomb, nullptr, ysb, 2048, 1024, 2);
  // x2 = gelu(ys + D*fx) + fx; fx2 = LN2(x2) -> E in place (bf16)
  k_ln2e<<<16384, 256, 0, stream>>>(ysb, E, Dv, ln2w, ln2b);
  // a-half -> a_b (bf16)
  k_gemm<3><<<1024, 256, 49152, stream>>>(E, ffeb, nullptr, a_b, nullptr, 1024, 1024, 3);
  // g-half + fused geglu (LDS epilogue) -> G (bf16)
  k_gemm<1><<<1024, 256, 49152, stream>>>(E, ffeb + (size_t)1024 * 1024, nullptr, G, a_b, 1024, 1024, 3);
  // ffo + residual(fx2) (LDS epilogue) -> x3b (bf16)
  k_gemm<2><<<1024, 256, 49152, stream>>>(G, ffdb, nullptr, x3b, E, 1024, 1024, 3);
  // out = x3 @ W_out^T (f32)
  k_gemm<0><<<512, 256, 49152, stream>>>(x3b, woutb, out, nullptr, nullptr, 1024, 512, 2);
}

// Round 18
// 438.056 us; speedup vs baseline: 1.0627x; 1.0218x over previous
//
#include <hip/hip_runtime.h>
#include <cstdint>

typedef __bf16 bf16;
typedef __bf16 bf16x2 __attribute__((ext_vector_type(2)));
typedef __bf16 bf16x4 __attribute__((ext_vector_type(4)));
typedef __bf16 bf16x8 __attribute__((ext_vector_type(8)));
typedef float f32x4 __attribute__((ext_vector_type(4)));

#define MROWS 16384
#define DIMH 1024
#define PDIM 512
#define LSEQ 4096
#define CL 16
#define NC (LSEQ / CL)  // 256

typedef const __attribute__((address_space(1))) unsigned int* gas_t;
typedef __attribute__((address_space(3))) unsigned int* las_t;

__device__ __forceinline__ float gelu_f(float x) {
  return 0.5f * x * (1.0f + erff(x * 0.70710678118654752f));
}

// ---------------------------------------------------------------- mega prep
__global__ __launch_bounds__(256) void k_mega(
    const float* __restrict__ x, const float* __restrict__ W_in,
    const float* __restrict__ W_out, const float* __restrict__ ffe,
    const float* __restrict__ ffd, const float* __restrict__ Lre,
    const float* __restrict__ Lim, const float* __restrict__ lstep,
    const float* __restrict__ Bre, const float* __restrict__ Bim,
    const float* __restrict__ Cre, const float* __restrict__ Cim,
    bf16* __restrict__ xb, bf16* __restrict__ winb, bf16* __restrict__ woutb,
    bf16* __restrict__ ffeb, bf16* __restrict__ ffdb, bf16* __restrict__ bcat,
    bf16* __restrict__ cc, float2* __restrict__ lamb) {
  const int bid = blockIdx.x;
  const int tid = threadIdx.x;
  auto cvt4 = [&](const float* src, bf16* dst, int i4) {
    const float4 v = *(const float4*)(src + i4);
    bf16x4 o = { (bf16)v.x, (bf16)v.y, (bf16)v.z, (bf16)v.w };
    *(bf16x4*)(dst + i4) = o;
  };
  if (bid < 8192) {
    cvt4(x, xb, bid * 1024 + tid * 4);
  } else if (bid < 8704) {
    cvt4(W_in, winb, (bid - 8192) * 1024 + tid * 4);
  } else if (bid < 9216) {
    cvt4(W_out, woutb, (bid - 8704) * 1024 + tid * 4);
  } else if (bid < 11264) {
    cvt4(ffe, ffeb, (bid - 9216) * 1024 + tid * 4);
  } else if (bid < 12288) {
    cvt4(ffd, ffdb, (bid - 11264) * 1024 + tid * 4);
  } else if (bid < 12800) {
    const int i4 = (bid - 12288) * 1024 + tid * 4;
    const int p = i4 >> 10;
    const float lre = Lre[p], lim = Lim[p];
    const float st = expf(lstep[p]);
    const float er = expf(lre * st);
    const float lbr = er * cosf(lim * st);
    const float lbi = er * sinf(lim * st);
    const float ar = lbr - 1.0f, ai = lbi;
    const float d = lre * lre + lim * lim;
    const float cx = (ar * lre + ai * lim) / d;
    const float cy = (ai * lre - ar * lim) / d;
    const float4 br = *(const float4*)(Bre + i4);
    const float4 bi = *(const float4*)(Bim + i4);
    bf16x4 o1 = { (bf16)(cx * br.x - cy * bi.x), (bf16)(cx * br.y - cy * bi.y),
                  (bf16)(cx * br.z - cy * bi.z), (bf16)(cx * br.w - cy * bi.w) };
    bf16x4 o2 = { (bf16)(cx * bi.x + cy * br.x), (bf16)(cx * bi.y + cy * br.y),
                  (bf16)(cx * bi.z + cy * br.z), (bf16)(cx * bi.w + cy * br.w) };
    *(bf16x4*)(bcat + i4) = o1;
    *(bf16x4*)(bcat + i4 + PDIM * DIMH) = o2;
  } else if (bid < 14848) {
    const int i4 = (bid - 12800) * 1024 + tid * 4;
    const int n = i4 >> 11, k0 = i4 & 2047;
    const float* src;
    float sgn;
    int kk;
    if (k0 < 512)       { src = Cre + n * 1024;       sgn =  2.0f; kk = k0; }
    else if (k0 < 1024) { src = Cim + n * 1024;       sgn = -2.0f; kk = k0 - 512; }
    else if (k0 < 1536) { src = Cre + n * 1024 + 512; sgn =  2.0f; kk = k0 - 1024; }
    else                { src = Cim + n * 1024 + 512; sgn = -2.0f; kk = k0 - 1536; }
    const float4 v = *(const float4*)(src + kk);
    bf16x4 o = { (bf16)(sgn * v.x), (bf16)(sgn * v.y), (bf16)(sgn * v.z), (bf16)(sgn * v.w) };
    *(bf16x4*)(cc + i4) = o;
  } else {
    const int p = (bid - 14848) * 256 + tid;
    if (p < PDIM) {
      const float lre = Lre[p], lim = Lim[p];
      const float st = expf(lstep[p]);
      const float er = expf(lre * st);
      lamb[p] = make_float2(er * cosf(lim * st), er * sinf(lim * st));
    }
  }
}

#define VMCNT4 asm volatile("s_waitcnt vmcnt(4)" ::: "memory")
#define VMCNT0 asm volatile("s_waitcnt vmcnt(0)" ::: "memory")
#define LGKM0  asm volatile("s_waitcnt lgkmcnt(0)" ::: "memory")
#define SCHED0 __builtin_amdgcn_sched_barrier(0)
#define BAR    __builtin_amdgcn_s_barrier()

// ---------------------------------------------------------------- GEMM A (128x128, 3-buffer, 1 barrier/unit, 3 blocks/CU)
// EPI: 0 = f32 store; 1 = bf16(auxb * gelu(acc)); 2 = bf16(acc + auxb); 3 = bf16.
// EPI 1/2: LDS-staged epilogue; consumer mapping row=slab*16+(tid>>4),
// col=(tid&15)*8 -> 256B-contiguous global loads/stores per 16-lane run.
template <int EPI>
__global__ __launch_bounds__(256, 3) void k_gemm(const bf16* __restrict__ A,
                                                 const bf16* __restrict__ W,
                                                 float* __restrict__ Cf,
                                                 bf16* __restrict__ Cb,
                                                 const bf16* __restrict__ auxb,
                                                 int K, int N, int nbnl) {
  extern __shared__ char lds[];  // 49152 bytes: 3 x (A 8KB + B 8KB)
  const int q = (int)gridDim.x >> 3;
  const int s = ((int)blockIdx.x & 7) * q + ((int)blockIdx.x >> 3);
  const int bm = s >> nbnl;
  const int bn = s & ((1 << nbnl) - 1);
  const int tid = threadIdx.x;
  const int lane = tid & 63;
  const int wave = tid >> 6;   // 0..3
  const int wr = wave >> 1;    // 0..1
  const int wc = wave & 1;     // 0..1

  const size_t arow0 = (size_t)bm * 128;
  const size_t wrow0 = (size_t)bn * 128;
  const int srow = tid >> 2;                         // 0..63 per issue
  const int schunk = (tid & 3) ^ ((tid >> 3) & 3);   // inverse-swizzled src chunk
  const int wbase = wave << 10;

  f32x4 acc[4][4];
#pragma unroll
  for (int i = 0; i < 4; ++i)
#pragma unroll
    for (int j = 0; j < 4; ++j) acc[i][j] = (f32x4){0.f, 0.f, 0.f, 0.f};

  auto stage = [&](int buf, int ui) {
    const int kcol = ui * 32 + schunk * 8;
    char* ba = lds + buf * 16384;
    __builtin_amdgcn_global_load_lds(
        (gas_t)(A + (arow0 + srow) * (size_t)K + kcol), (las_t)(ba + wbase), 16, 0, 0);
    __builtin_amdgcn_global_load_lds(
        (gas_t)(A + (arow0 + 64 + srow) * (size_t)K + kcol), (las_t)(ba + 4096 + wbase), 16, 0, 0);
    char* bb = ba + 8192;
    __builtin_amdgcn_global_load_lds(
        (gas_t)(W + (wrow0 + srow) * (size_t)K + kcol), (las_t)(bb + wbase), 16, 0, 0);
    __builtin_amdgcn_global_load_lds(
        (gas_t)(W + (wrow0 + 64 + srow) * (size_t)K + kcol), (las_t)(bb + 4096 + wbase), 16, 0, 0);
  };

  auto ldA = [&](int buf, bf16x8* af) {
#pragma unroll
    for (int m = 0; m < 4; ++m) {
      const int row = wr * 64 + m * 16 + (lane & 15);
      const int pc = (lane >> 4) ^ ((row >> 1) & 3);
      af[m] = *(const bf16x8*)(lds + buf * 16384 + row * 64 + pc * 16);
    }
  };
  auto ldB = [&](int buf, bf16x8* bf) {
#pragma unroll
    for (int n = 0; n < 4; ++n) {
      const int row = wc * 64 + n * 16 + (lane & 15);
      const int pc = (lane >> 4) ^ ((row >> 1) & 3);
      bf[n] = *(const bf16x8*)(lds + buf * 16384 + 8192 + row * 64 + pc * 16);
    }
  };

  bf16x8 afr[4], bfr[4];

  stage(0, 0);
  stage(1, 1);
  VMCNT4;
  BAR;

  const int NU = K >> 5;  // units of 32 K-cols
  int buf = 0, sbuf = 2;
  for (int u = 0; u < NU; ++u) {
    ldB(buf, bfr);
    ldA(buf, afr);
    if (u + 2 < NU) stage(sbuf, u + 2);
    LGKM0; SCHED0;
    __builtin_amdgcn_s_setprio(1);
#pragma unroll
    for (int m = 0; m < 4; ++m)
#pragma unroll
      for (int n = 0; n < 4; ++n)
        acc[m][n] = __builtin_amdgcn_mfma_f32_16x16x32_bf16(afr[m], bfr[n], acc[m][n], 0, 0, 0);
    __builtin_amdgcn_s_setprio(0);
    SCHED0;
    if (u + 2 < NU) { VMCNT4; }
    else if (u + 1 < NU) { VMCNT0; }
    BAR;
    buf = (buf == 2) ? 0 : buf + 1;
    sbuf = (sbuf == 2) ? 0 : sbuf + 1;
  }

  if constexpr (EPI == 1 || EPI == 2) {
    // LDS-staged coalesced epilogue (fenced barriers).
    float* sml = (float*)lds;
    __syncthreads();  // all waves' final frag reads retired before overwrite
#pragma unroll
    for (int h = 0; h < 2; ++h) {
      if (wr == h) {
#pragma unroll
        for (int mi = 0; mi < 4; ++mi)
#pragma unroll
          for (int n = 0; n < 4; ++n) {
            const int lrow0 = mi * 16 + ((lane >> 4) << 2);
            const int lcol = wc * 64 + (lane & 15) + n * 16;
#pragma unroll
            for (int r = 0; r < 4; ++r)
              sml[(lrow0 + r) * 132 + lcol] = acc[mi][n][r];
          }
      }
      __syncthreads();
      const int rb = tid >> 4;        // 0..15
      const int c0 = (tid & 15) * 8;  // 0..120
#pragma unroll
      for (int slab = 0; slab < 4; ++slab) {
        const int lrow = slab * 16 + rb;
        const size_t goff = (arow0 + h * 64 + lrow) * (size_t)N + wrow0 + c0;
        const float* sp = sml + lrow * 132 + c0;
        const bf16x8 a8 = *(const bf16x8*)(auxb + goff);
        bf16x8 o8;
#pragma unroll
        for (int e = 0; e < 8; ++e) {
          const float v = sp[e];
          if constexpr (EPI == 1) o8[e] = (bf16)((float)a8[e] * gelu_f(v));
          else                    o8[e] = (bf16)(v + (float)a8[e]);
        }
        *(bf16x8*)(Cb + goff) = o8;
      }
      if (h == 0) __syncthreads();  // half-0 reads done before half-1 writes
    }
  } else {
    const int n0 = (int)wrow0 + wc * 64 + (lane & 15);
    const size_t m0 = arow0 + wr * 64 + ((lane >> 4) << 2);
#pragma unroll
    for (int mi = 0; mi < 4; ++mi)
#pragma unroll
      for (int n = 0; n < 4; ++n) {
        const size_t mb = m0 + mi * 16;
        const int nn = n0 + n * 16;
#pragma unroll
        for (int r = 0; r < 4; ++r) {
          const size_t idx = (mb + r) * (size_t)N + nn;
          const float v = acc[mi][n][r];
          if constexpr (EPI == 0) {
            Cf[idx] = v;
          } else {
            Cb[idx] = (bf16)v;
          }
        }
      }
  }
}

// ---------------------------------------------------------------- GEMM B (256x256, 3-buffer rotation, 1 barrier/unit)
// For K=2048 (C-proj). unit = 32 K-cols, LDS 3 x (A 16KB + B 16KB) = 96 KB.
template <int EPI>
__global__ __launch_bounds__(512, 1) void k_gemm2(const bf16* __restrict__ A,
                                                  const bf16* __restrict__ W,
                                                  float* __restrict__ Cf,
                                                  bf16* __restrict__ Cb,
                                                  int K, int N, int nbnl) {
  extern __shared__ char lds[];  // 98304 bytes
  const int q = (int)gridDim.x >> 3;
  const int s = ((int)blockIdx.x & 7) * q + ((int)blockIdx.x >> 3);
  const int bm = s >> nbnl;
  const int bn = s & ((1 << nbnl) - 1);
  const int tid = threadIdx.x;
  const int lane = tid & 63;
  const int wave = tid >> 6;
  const int wr = wave >> 2;  // 0..1
  const int wc = wave & 3;   // 0..3

  const size_t arow0 = (size_t)bm * 256;
  const size_t wrow0 = (size_t)bn * 256;
  const int srow = tid >> 2;                         // 0..127 per issue
  const int schunk = (tid & 3) ^ ((tid >> 3) & 3);
  const int wbase = wave << 10;

  f32x4 acc[8][4];
#pragma unroll
  for (int i = 0; i < 8; ++i)
#pragma unroll
    for (int j = 0; j < 4; ++j) acc[i][j] = (f32x4){0.f, 0.f, 0.f, 0.f};

  auto stage = [&](int buf, int ui) {
    const int kcol = ui * 32 + schunk * 8;
    char* ba = lds + buf * 32768;
    __builtin_amdgcn_global_load_lds(
        (gas_t)(A + (arow0 + srow) * (size_t)K + kcol), (las_t)(ba + wbase), 16, 0, 0);
    __builtin_amdgcn_global_load_lds(
        (gas_t)(A + (arow0 + 128 + srow) * (size_t)K + kcol), (las_t)(ba + 8192 + wbase), 16, 0, 0);
    char* bb = ba + 16384;
    __builtin_amdgcn_global_load_lds(
        (gas_t)(W + (wrow0 + srow) * (size_t)K + kcol), (las_t)(bb + wbase), 16, 0, 0);
    __builtin_amdgcn_global_load_lds(
        (gas_t)(W + (wrow0 + 128 + srow) * (size_t)K + kcol), (las_t)(bb + 8192 + wbase), 16, 0, 0);
  };

  auto ldA = [&](int buf, bf16x8* af) {
#pragma unroll
    for (int m = 0; m < 8; ++m) {
      const int row = wr * 128 + m * 16 + (lane & 15);
      const int pc = (lane >> 4) ^ ((row >> 1) & 3);
      af[m] = *(const bf16x8*)(lds + buf * 32768 + row * 64 + pc * 16);
    }
  };
  auto ldB = [&](int buf, bf16x8* bf) {
#pragma unroll
    for (int n = 0; n < 4; ++n) {
      const int row = wc * 64 + n * 16 + (lane & 15);
      const int pc = (lane >> 4) ^ ((row >> 1) & 3);
      bf[n] = *(const bf16x8*)(lds + buf * 32768 + 16384 + row * 64 + pc * 16);
    }
  };

  bf16x8 afr[8], bfr[4];

  stage(0, 0);
  stage(1, 1);
  VMCNT4;
  BAR;

  const int NU = K >> 5;  // 64 units for K=2048
  int buf = 0, sbuf = 2;
  for (int u = 0; u < NU; ++u) {
    ldB(buf, bfr);
    ldA(buf, afr);
    if (u + 2 < NU) stage(sbuf, u + 2);
    LGKM0; SCHED0;
    __builtin_amdgcn_s_setprio(1);
#pragma unroll
    for (int m = 0; m < 8; ++m)
#pragma unroll
      for (int n = 0; n < 4; ++n)
        acc[m][n] = __builtin_amdgcn_mfma_f32_16x16x32_bf16(afr[m], bfr[n], acc[m][n], 0, 0, 0);
    __builtin_amdgcn_s_setprio(0);
    SCHED0;
    if (u + 2 < NU) { VMCNT4; }
    else if (u + 1 < NU) { VMCNT0; }
    BAR;
    buf = (buf == 2) ? 0 : buf + 1;
    sbuf = (sbuf == 2) ? 0 : sbuf + 1;
  }

  const int n0 = (int)wrow0 + wc * 64 + (lane & 15);
  const size_t m0 = arow0 + wr * 128 + ((lane >> 4) << 2);
#pragma unroll
  for (int mi = 0; mi < 8; ++mi)
#pragma unroll
    for (int n = 0; n < 4; ++n) {
      const size_t mb = m0 + mi * 16;
      const int nn = n0 + n * 16;
#pragma unroll
      for (int r = 0; r < 4; ++r) {
        const size_t idx = (mb + r) * (size_t)N + nn;
        const float v = acc[mi][n][r];
        if constexpr (EPI == 0) {
          Cf[idx] = v;
        } else {
          Cb[idx] = (bf16)v;
        }
      }
    }
}

// ---------------------------------------------------------------- LayerNorm (bf16 in/out)
__global__ __launch_bounds__(256) void k_ln(const bf16* __restrict__ X,
                                            const float* __restrict__ w,
                                            const float* __restrict__ bb,
                                            bf16* __restrict__ Yb) {
  const int m = blockIdx.x;
  const int tid = threadIdx.x;
  const bf16x4 v4 = *(const bf16x4*)(X + (size_t)m * DIMH + tid * 4);
  const float v0 = (float)v4[0], v1 = (float)v4[1], v2 = (float)v4[2], v3 = (float)v4[3];
  float s = v0 + v1 + v2 + v3;
  float s2 = v0 * v0 + v1 * v1 + v2 * v2 + v3 * v3;
#pragma unroll
  for (int off = 32; off > 0; off >>= 1) { s += __shfl_down(s, off); s2 += __shfl_down(s2, off); }
  __shared__ float rs[4], rq[4];
  if ((tid & 63) == 0) { rs[tid >> 6] = s; rq[tid >> 6] = s2; }
  __syncthreads();
  s = rs[0] + rs[1] + rs[2] + rs[3];
  s2 = rq[0] + rq[1] + rq[2] + rq[3];
  const float mu = s * (1.0f / DIMH);
  const float inv = rsqrtf(s2 * (1.0f / DIMH) - mu * mu + 1e-5f);
  const float4 wv = ((const float4*)w)[tid];
  const float4 bv = ((const float4*)bb)[tid];
  bf16x4 ob = { (bf16)((v0 - mu) * inv * wv.x + bv.x), (bf16)((v1 - mu) * inv * wv.y + bv.y),
                (bf16)((v2 - mu) * inv * wv.z + bv.z), (bf16)((v3 - mu) * inv * wv.w + bv.w) };
  *(bf16x4*)(Yb + (size_t)m * DIMH + tid * 4) = ob;
}

// fused: t = gelu(ys + D*fx) + fx ; LN(t) -> fx2, in-place into FXE
__global__ __launch_bounds__(256) void k_ln2e(const bf16* __restrict__ YS,
                                              bf16* FXE,
                                              const float* __restrict__ Dv,
                                              const float* __restrict__ w,
                                              const float* __restrict__ bb) {
  const int m = blockIdx.x;
  const int tid = threadIdx.x;
  const bf16x4 ys4 = *(const bf16x4*)(YS + (size_t)m * DIMH + tid * 4);
  const bf16x4 fx4 = *(const bf16x4*)(FXE + (size_t)m * DIMH + tid * 4);
  const float4 dv = ((const float4*)Dv)[tid];
  const float f0 = (float)fx4[0], f1 = (float)fx4[1], f2 = (float)fx4[2], f3 = (float)fx4[3];
  const float t0 = gelu_f((float)ys4[0] + dv.x * f0) + f0;
  const float t1 = gelu_f((float)ys4[1] + dv.y * f1) + f1;
  const float t2 = gelu_f((float)ys4[2] + dv.z * f2) + f2;
  const float t3 = gelu_f((float)ys4[3] + dv.w * f3) + f3;
  float s = t0 + t1 + t2 + t3;
  float s2 = t0 * t0 + t1 * t1 + t2 * t2 + t3 * t3;
#pragma unroll
  for (int off = 32; off > 0; off >>= 1) { s += __shfl_down(s, off); s2 += __shfl_down(s2, off); }
  __shared__ float rs[4], rq[4];
  if ((tid & 63) == 0) { rs[tid >> 6] = s; rq[tid >> 6] = s2; }
  __syncthreads();
  s = rs[0] + rs[1] + rs[2] + rs[3];
  s2 = rq[0] + rq[1] + rq[2] + rq[3];
  const float mu = s * (1.0f / DIMH);
  const float inv = rsqrtf(s2 * (1.0f / DIMH) - mu * mu + 1e-5f);
  const float4 wv = ((const float4*)w)[tid];
  const float4 bv = ((const float4*)bb)[tid];
  bf16x4 ob = { (bf16)((t0 - mu) * inv * wv.x + bv.x), (bf16)((t1 - mu) * inv * wv.y + bv.y),
                (bf16)((t2 - mu) * inv * wv.z + bv.z), (bf16)((t3 - mu) * inv * wv.w + bv.w) };
  *(bf16x4*)(FXE + (size_t)m * DIMH + tid * 4) = ob;
}

// ---------------------------------------------------------------- scan (3-pass, bf16 Bu)
__global__ __launch_bounds__(256) void k_scanA(const bf16* __restrict__ Bu,
                                               const float2* __restrict__ lamb,
                                               float2* __restrict__ carry) {
  const int bc = blockIdx.x;
  const int b = bc >> 8, c = bc & (NC - 1);
  const int t = threadIdx.x;
  const size_t rbase = ((size_t)b * LSEQ + (size_t)c * CL) * DIMH;
  float2 re[CL], im[CL];
#pragma unroll
  for (int i = 0; i < CL; ++i) {
    const bf16x2 r2 = *(const bf16x2*)(Bu + rbase + (size_t)i * DIMH + 2 * t);
    const bf16x2 i2 = *(const bf16x2*)(Bu + rbase + (size_t)i * DIMH + PDIM + 2 * t);
    re[i] = make_float2((float)r2[0], (float)r2[1]);
    im[i] = make_float2((float)i2[0], (float)i2[1]);
  }
  const float2 l0 = lamb[2 * t];
  const float2 l1 = lamb[2 * t + 1];
  const size_t cb = ((size_t)bc * 2) * PDIM;
  {
    float s0r = 0.f, s0i = 0.f, s1r = 0.f, s1i = 0.f;
#pragma unroll
    for (int i = 0; i < CL; ++i) {
      float nr = l0.x * s0r - l0.y * s0i + re[i].x;
      float ni = l0.x * s0i + l0.y * s0r + im[i].x;
      s0r = nr; s0i = ni;
      nr = l1.x * s1r - l1.y * s1i + re[i].y;
      ni = l1.x * s1i + l1.y * s1r + im[i].y;
      s1r = nr; s1i = ni;
    }
    carry[cb + 2 * t]     = make_float2(s0r, s0i);
    carry[cb + 2 * t + 1] = make_float2(s1r, s1i);
  }
  {
    float s0r = 0.f, s0i = 0.f, s1r = 0.f, s1i = 0.f;
#pragma unroll
    for (int i = CL - 1; i >= 0; --i) {
      float nr = l0.x * s0r - l0.y * s0i + re[i].x;
      float ni = l0.x * s0i + l0.y * s0r + im[i].x;
      s0r = nr; s0i = ni;
      nr = l1.x * s1r - l1.y * s1i + re[i].y;
      ni = l1.x * s1i + l1.y * s1r + im[i].y;
      s1r = nr; s1i = ni;
    }
    carry[cb + PDIM + 2 * t]     = make_float2(s0r, s0i);
    carry[cb + PDIM + 2 * t + 1] = make_float2(s1r, s1i);
  }
}

__global__ __launch_bounds__(256) void k_scanB(const float2* __restrict__ carry,
                                               const float2* __restrict__ lamb,
                                               float2* __restrict__ seed) {
  const int b = blockIdx.x;  // 4 blocks
  const int t = threadIdx.x;
  const float2 l0 = lamb[2 * t], l1 = lamb[2 * t + 1];
  float L0r = l0.x, L0i = l0.y, L1r = l1.x, L1i = l1.y;
#pragma unroll
  for (int q = 0; q < 4; ++q) {
    float tr = L0r * L0r - L0i * L0i; L0i = 2.f * L0r * L0i; L0r = tr;
    tr = L1r * L1r - L1i * L1i; L1i = 2.f * L1r * L1i; L1r = tr;
  }
  float S0r = 0.f, S0i = 0.f, S1r = 0.f, S1i = 0.f;
  for (int c = 0; c < NC; ++c) {
    const size_t base = (((size_t)b * NC + c) * 2) * PDIM;
    const float2 c0 = carry[base + 2 * t];
    const float2 c1 = carry[base + 2 * t + 1];
    seed[base + 2 * t]     = make_float2(S0r, S0i);
    seed[base + 2 * t + 1] = make_float2(S1r, S1i);
    float nr = L0r * S0r - L0i * S0i + c0.x;
    float ni = L0r * S0i + L0i * S0r + c0.y;
    S0r = nr; S0i = ni;
    nr = L1r * S1r - L1i * S1i + c1.x;
    ni = L1r * S1i + L1i * S1r + c1.y;
    S1r = nr; S1i = ni;
  }
  S0r = 0.f; S0i = 0.f; S1r = 0.f; S1i = 0.f;
  for (int c = NC - 1; c >= 0; --c) {
    const size_t base = (((size_t)b * NC + c) * 2) * PDIM + PDIM;
    const float2 c0 = carry[base + 2 * t];
    const float2 c1 = carry[base + 2 * t + 1];
    seed[base + 2 * t]     = make_float2(S0r, S0i);
    seed[base + 2 * t + 1] = make_float2(S1r, S1i);
    float nr = L0r * S0r - L0i * S0i + c0.x;
    float ni = L0r * S0i + L0i * S0r + c0.y;
    S0r = nr; S0i = ni;
    nr = L1r * S1r - L1i * S1i + c1.x;
    ni = L1r * S1i + L1i * S1r + c1.y;
    S1r = nr; S1i = ni;
  }
}

__global__ __launch_bounds__(256) void k_scanC(const bf16* __restrict__ Bu,
                                               const float2* __restrict__ lamb,
                                               const float2* __restrict__ seed,
                                               bf16* __restrict__ xs) {
  const int bc = blockIdx.x;
  const int b = bc >> 8, c = bc & (NC - 1);
  const int t = threadIdx.x;
  const size_t rbase = ((size_t)b * LSEQ + (size_t)c * CL) * DIMH;
  float2 re[CL], im[CL];
#pragma unroll
  for (int i = 0; i < CL; ++i) {
    const bf16x2 r2 = *(const bf16x2*)(Bu + rbase + (size_t)i * DIMH + 2 * t);
    const bf16x2 i2 = *(const bf16x2*)(Bu + rbase + (size_t)i * DIMH + PDIM + 2 * t);
    re[i] = make_float2((float)r2[0], (float)r2[1]);
    im[i] = make_float2((float)i2[0], (float)i2[1]);
  }
  const float2 l0 = lamb[2 * t];
  const float2 l1 = lamb[2 * t + 1];
  const size_t sb = ((size_t)bc * 2) * PDIM;
  const size_t obase = ((size_t)b * LSEQ + (size_t)c * CL) * 2048;
  {
    const float2 s0 = seed[sb + 2 * t];
    const float2 s1 = seed[sb + 2 * t + 1];
    float s0r = s0.x, s0i = s0.y, s1r = s1.x, s1i = s1.y;
#pragma unroll
    for (int i = 0; i < CL; ++i) {
      float nr = l0.x * s0r - l0.y * s0i + re[i].x;
      float ni = l0.x * s0i + l0.y * s0r + im[i].x;
      s0r = nr; s0i = ni;
      nr = l1.x * s1r - l1.y * s1i + re[i].y;
      ni = l1.x * s1i + l1.y * s1r + im[i].y;
      s1r = nr; s1i = ni;
      bf16x2 wr2 = { (bf16)s0r, (bf16)s1r };
      bf16x2 wi2 = { (bf16)s0i, (bf16)s1i };
      *(bf16x2*)(xs + obase + (size_t)i * 2048 + 2 * t) = wr2;
      *(bf16x2*)(xs + obase + (size_t)i * 2048 + PDIM + 2 * t) = wi2;
    }
  }
  {
    const float2 s0 = seed[sb + PDIM + 2 * t];
    const float2 s1 = seed[sb + PDIM + 2 * t + 1];
    float s0r = s0.x, s0i = s0.y, s1r = s1.x, s1i = s1.y;
#pragma unroll
    for (int i = CL - 1; i >= 0; --i) {
      float nr = l0.x * s0r - l0.y * s0i + re[i].x;
      float ni = l0.x * s0i + l0.y * s0r + im[i].x;
      s0r = nr; s0i = ni;
      nr = l1.x * s1r - l1.y * s1i + re[i].y;
      ni = l1.x * s1i + l1.y * s1r + im[i].y;
      s1r = nr; s1i = ni;
      bf16x2 wr2 = { (bf16)s0r, (bf16)s1r };
      bf16x2 wi2 = { (bf16)s0i, (bf16)s1i };
      *(bf16x2*)(xs + obase + (size_t)i * 2048 + 1024 + 2 * t) = wr2;
      *(bf16x2*)(xs + obase + (size_t)i * 2048 + 1536 + 2 * t) = wi2;
    }
  }
}

// ---------------------------------------------------------------- launch
extern "C" void kernel_launch(void* const* d_in, const int* in_sizes, int n_in,
                              void* d_out, int out_size, void* d_ws, size_t ws_size,
                              hipStream_t stream) {
  const float* x    = (const float*)d_in[0];
  const float* W_in = (const float*)d_in[1];
  const float* W_out= (const float*)d_in[2];
  const float* ln1w = (const float*)d_in[3];
  const float* ln1b = (const float*)d_in[4];
  const float* ln2w = (const float*)d_in[5];
  const float* ln2b = (const float*)d_in[6];
  const float* Lre  = (const float*)d_in[7];
  const float* Lim  = (const float*)d_in[8];
  const float* lstep= (const float*)d_in[9];
  const float* Bre  = (const float*)d_in[10];
  const float* Bim  = (const float*)d_in[11];
  const float* Cre  = (const float*)d_in[12];
  const float* Cim  = (const float*)d_in[13];
  const float* Dv   = (const float*)d_in[14];
  const float* ffe  = (const float*)d_in[15];
  const float* ffd  = (const float*)d_in[16];
  float* out = (float*)d_out;
  char* ws = (char*)d_ws;

  bf16* winb   = (bf16*)(ws);
  bf16* woutb  = (bf16*)(ws + (1u << 20));
  bf16* bcat   = (bf16*)(ws + (2u << 20));
  bf16* ccomb  = (bf16*)(ws + (4u << 20));
  bf16* ffeb   = (bf16*)(ws + (8u << 20));
  bf16* ffdb   = (bf16*)(ws + (12u << 20));
  float2* lamb = (float2*)(ws + (14u << 20));
  bf16* E      = (bf16*)(ws + (16u << 20));        // 32MB: x_b -> fx -> fx2
  bf16* hb     = (bf16*)(ws + (48u << 20));        // 32MB: h
  bf16* Bub    = (bf16*)(ws + (48u << 20));        // reuse (h dead after k_ln)
  bf16* ysb    = (bf16*)(ws + (48u << 20));        // reuse (Bu dead after scanC)
  bf16* x3b    = (bf16*)(ws + (48u << 20));        // reuse (ys dead after ln2e)
  bf16* xsb    = (bf16*)(ws + (80u << 20));        // 64MB: xs
  bf16* a_b    = (bf16*)(ws + (80u << 20));        // reuse (xs dead after C-proj)
  bf16* G      = (bf16*)(ws + (112u << 20));       // 32MB
  float2* carry = (float2*)(ws + (144u << 20));    // 8MB
  float2* seed  = (float2*)(ws + (152u << 20));    // 8MB

  static bool attr_done = false;
  if (!attr_done) {
    (void)hipFuncSetAttribute((const void*)&k_gemm<0>, hipFuncAttributeMaxDynamicSharedMemorySize, 49152);
    (void)hipFuncSetAttribute((const void*)&k_gemm<1>, hipFuncAttributeMaxDynamicSharedMemorySize, 49152);
    (void)hipFuncSetAttribute((const void*)&k_gemm<2>, hipFuncAttributeMaxDynamicSharedMemorySize, 49152);
    (void)hipFuncSetAttribute((const void*)&k_gemm<3>, hipFuncAttributeMaxDynamicSharedMemorySize, 49152);
    (void)hipFuncSetAttribute((const void*)&k_gemm2<3>, hipFuncAttributeMaxDynamicSharedMemorySize, 98304);
    attr_done = true;
  }

  // prep: one mega launch
  k_mega<<<14850, 256, 0, stream>>>(x, W_in, W_out, ffe, ffd, Lre, Lim, lstep,
                                    Bre, Bim, Cre, Cim,
                                    E, winb, woutb, ffeb, ffdb, bcat, ccomb, lamb);

  // h = x @ W_in^T -> hb (bf16)
  k_gemm<3><<<1024, 256, 49152, stream>>>(E, winb, nullptr, hb, nullptr, 512, 1024, 3);
  // fx = LN1(h) -> E (bf16)
  k_ln<<<16384, 256, 0, stream>>>(hb, ln1w, ln1b, E);
  // Bu = fx @ Bcat^T -> Bub (bf16)
  k_gemm<3><<<1024, 256, 49152, stream>>>(E, bcat, nullptr, Bub, nullptr, 1024, 1024, 3);
  // xs -> xsb (bf16) via 3-pass chunked scan
  k_scanA<<<4 * NC, 256, 0, stream>>>(Bub, lamb, carry);
  k_scanB<<<4, 256, 0, stream>>>(carry, lamb, seed);
  k_scanC<<<4 * NC, 256, 0, stream>>>(Bub, lamb, seed, xsb);
  // ys = xs @ Ccomb^T -> ysb (bf16): 256x256 3-buffer kernel (K=2048)
  k_gemm2<3><<<256, 512, 98304, stream>>>(xsb, ccomb, nullptr, ysb, 2048, 1024, 2);
  // x2 = gelu(ys + D*fx) + fx; fx2 = LN2(x2) -> E in place (bf16)
  k_ln2e<<<16384, 256, 0, stream>>>(ysb, E, Dv, ln2w, ln2b);
  // a-half -> a_b (bf16)
  k_gemm<3><<<1024, 256, 49152, stream>>>(E, ffeb, nullptr, a_b, nullptr, 1024, 1024, 3);
  // g-half + fused geglu (LDS epilogue) -> G (bf16)
  k_gemm<1><<<1024, 256, 49152, stream>>>(E, ffeb + (size_t)1024 * 1024, nullptr, G, a_b, 1024, 1024, 3);
  // ffo + residual(fx2) (LDS epilogue) -> x3b (bf16)
  k_gemm<2><<<1024, 256, 49152, stream>>>(G, ffdb, nullptr, x3b, E, 1024, 1024, 3);
  // out = x3 @ W_out^T (f32)
  k_gemm<0><<<512, 256, 49152, stream>>>(x3b, woutb, out, nullptr, nullptr, 1024, 512, 2);
}